// Round 2
// baseline (509.410 us; speedup 1.0000x reference)
//
#include <hip/hip_runtime.h>

#define NN 10000
#define NE 400000
#define HD 128
#define NIN 6
#define EDIM 3
#define NL 4
#define CAP 96
#define NCH 6
#define LN_EPS 1e-5f

typedef unsigned short u16;
using short8 = __attribute__((ext_vector_type(8))) short;
using f32x4 = __attribute__((ext_vector_type(4))) float;

__device__ __forceinline__ u16 f2bf(float x) {
    unsigned u = __float_as_uint(x);
    return (u16)((u + 0x7fff + ((u >> 16) & 1)) >> 16);
}
__device__ __forceinline__ float bf2f(u16 h) { return __uint_as_float(((unsigned)h) << 16); }
__device__ __forceinline__ void split2(float x, u16& hi, u16& lo) {
    hi = f2bf(x);
    lo = f2bf(x - bf2f(hi));
}
#define MFMA(a, b, c) __builtin_amdgcn_mfma_f32_16x16x32_bf16((a), (b), (c), 0, 0, 0)

// ---- k_prepscat: weight prep (blocks [0,442)) + edge scatter (blocks [442,...)).
// cnt zeroed by hipMemsetAsync before this kernel.
// prep idx ranges:
// [0,65536)       M2-dot (l,i,jj) -> fG1 hi-half element (k=128+i, n=jj)
// [65536,66048)   c2
// [66048,76048)   dead
// [76048,84240)   fG1 lo-half | [84240,92432) fG2 | [92432,108816) fPQ
// [108816,110864) fDec | [110864,112912) fEnc

__global__ __launch_bounds__(256) void k_prepscat(
    const float* __restrict__ msg_w2, const float* __restrict__ msg_b2, const float* __restrict__ upd_w1,
    const float* __restrict__ upd_w2, const float* __restrict__ msg_w1, const float* __restrict__ dec_w1,
    const float* __restrict__ enc_w2, float* __restrict__ c2,
    u16* __restrict__ fG1, u16* __restrict__ fG2, u16* __restrict__ fPQ,
    u16* __restrict__ fDec, u16* __restrict__ fEnc,
    const int* __restrict__ srcp, const int* __restrict__ tgtp, const float* __restrict__ eattr,
    int* __restrict__ cnt, float4* __restrict__ sea) {
    if (blockIdx.x >= 442) {
        int e = (blockIdx.x - 442) * 256 + threadIdx.x;
        if (e < NE) {
            int t = tgtp[e];
            int pos = atomicAdd(&cnt[t], 1);
            if (pos < CAP) {
                sea[t * CAP + pos] = make_float4(eattr[e * 3], eattr[e * 3 + 1], eattr[e * 3 + 2],
                                                 __uint_as_float((unsigned)srcp[e]));
            }
        }
        return;
    }
    int idx = blockIdx.x * 256 + threadIdx.x;
    if (idx < 65536) {
        int l = idx >> 14, rem = idx & 16383, i = rem >> 7, jj = rem & 127;
        const float* U1b = upd_w1 + (size_t)l * 2 * HD * HD + (size_t)HD * HD;
        const float* W2 = msg_w2 + (size_t)l * HD * HD + (size_t)i * HD;
        float acc = 0.f;
        for (int t = 0; t < HD; ++t) acc += W2[t] * U1b[(size_t)t * HD + jj];
        int ct = jj >> 4;
        int ks = 4 + (i >> 5);
        int lane = (((i & 31) >> 3) << 4) | (jj & 15);
        int j = i & 7;
        int g = (l << 12) | (ct << 9) | (ks << 6) | lane;
        fG1[(size_t)g * 8 + j] = f2bf(acc);
    } else if (idx < 66048) {
        int r = idx - 65536;
        int l = r >> 7, jj = r & 127;
        const float* U1b = upd_w1 + (size_t)l * 2 * HD * HD + (size_t)HD * HD;
        const float* b2 = msg_b2 + l * HD;
        float acc = 0.f;
        for (int t = 0; t < HD; ++t) acc += b2[t] * U1b[(size_t)t * HD + jj];
        c2[r] = acc;
    } else if (idx < 76048) {
        // dead
    } else if (idx < 84240) {
        int gl = idx - 76048;
        int l = gl >> 11, rem = gl & 2047;
        int ct = rem >> 8, ks = (rem >> 6) & 3, lane = rem & 63;
        int n = ct * 16 + (lane & 15), kb = ks * 32 + ((lane >> 4) << 3);
        int g = (l << 12) | (ct << 9) | (ks << 6) | lane;
        u16* dst = fG1 + (size_t)g * 8;
        const float* U = upd_w1 + (size_t)l * 256 * 128;
#pragma unroll
        for (int j = 0; j < 8; ++j) dst[j] = f2bf(U[(size_t)(kb + j) * 128 + n]);
    } else if (idx < 92432) {
        int gg = idx - 84240;
        int l = gg >> 11, r = gg & 2047;
        int ct = r >> 8, ks = (r >> 6) & 3, lane = r & 63;
        int n = ct * 16 + (lane & 15), kb = ks * 32 + ((lane >> 4) << 3);
        u16* dst = fG2 + (size_t)gg * 8;
        const float* W = upd_w2 + (size_t)l * 128 * 128;
#pragma unroll
        for (int j = 0; j < 8; ++j) dst[j] = f2bf(W[(size_t)(kb + j) * 128 + n]);
    } else if (idx < 108816) {
        int gg = idx - 92432;
        int li = gg >> 12, r = gg & 4095;
        int ct = r >> 8, ks = (r >> 6) & 3, lane = r & 63;
        int n = ct * 16 + (lane & 15), kb = ks * 32 + ((lane >> 4) << 3);
        u16* dst = fPQ + (size_t)gg * 8;
        const float* W = msg_w1 + (size_t)li * (2 * HD + EDIM) * HD;
#pragma unroll
        for (int j = 0; j < 8; ++j) {
            int k = kb + j;
            float v = (n < 128) ? W[(size_t)k * 128 + n] : W[(size_t)(128 + k) * 128 + (n - 128)];
            dst[j] = f2bf(v);
        }
    } else if (idx < 110864) {
        int r = idx - 108816;
        int ct = r >> 8, ks = (r >> 6) & 3, lane = r & 63;
        int n = ct * 16 + (lane & 15), kb = ks * 32 + ((lane >> 4) << 3);
        u16* dst = fDec + (size_t)r * 8;
#pragma unroll
        for (int j = 0; j < 8; ++j) dst[j] = f2bf(dec_w1[(size_t)(kb + j) * 128 + n]);
    } else if (idx < 112912) {
        int r = idx - 110864;
        int ct = r >> 8, ks = (r >> 6) & 3, lane = r & 63;
        int n = ct * 16 + (lane & 15), kb = ks * 32 + ((lane >> 4) << 3);
        u16* dst = fEnc + (size_t)r * 8;
#pragma unroll
        for (int j = 0; j < 8; ++j) dst[j] = f2bf(enc_w2[(size_t)(kb + j) * 128 + n]);
    }
}

// ---- k_enc: encoder (16 nodes per block) + PQ0 precompute ----

__global__ __launch_bounds__(512) void k_enc(
    const float* __restrict__ x, const float* __restrict__ ew1, const float* __restrict__ eb1,
    const u16* __restrict__ fEnc, const float* __restrict__ eb2, const u16* __restrict__ fPQ0,
    const float* __restrict__ mb1, u16* __restrict__ h_hi, u16* __restrict__ h_lo,
    float* __restrict__ PQf, u16* __restrict__ Qb) {
    __shared__ u16 tHi[2048], tLo[2048];
    int tid = threadIdx.x, w = tid >> 6, lane = tid & 63, q = lane >> 4, c = lane & 15;
    int band = blockIdx.x * 16;
    {
        int col = w * 16 + c;
        float wv[NIN];
#pragma unroll
        for (int k = 0; k < NIN; ++k) wv[k] = ew1[k * HD + col];
        float ebv = eb1[col];
#pragma unroll
        for (int reg = 0; reg < 4; ++reg) {
            int row = band + q * 4 + reg;
            float t = ebv;
#pragma unroll
            for (int k = 0; k < NIN; ++k) t += x[(size_t)row * NIN + k] * wv[k];
            t = fmaxf(t, 0.f);
            u16 hi, lo;
            split2(t, hi, lo);
            int r16 = q * 4 + reg;
            int a = r16 * 128 + (((col >> 3) ^ r16) << 3) + (col & 7);
            tHi[a] = hi;
            tLo[a] = lo;
        }
    }
    __syncthreads();
    short8 aH[4], aL[4];
#pragma unroll
    for (int ks = 0; ks < 4; ++ks) {
        int a = c * 128 + (((ks * 4 + q) ^ c) << 3);
        aH[ks] = *(const short8*)&tHi[a];
        aL[ks] = *(const short8*)&tLo[a];
    }
    f32x4 acc = {0, 0, 0, 0};
    {
        const u16* fb = fEnc + (size_t)w * 4 * 512 + lane * 8;
#pragma unroll
        for (int ks = 0; ks < 4; ++ks) {
            short8 b = *(const short8*)(fb + ks * 512);
            acc = MFMA(aH[ks], b, acc);
            acc = MFMA(aL[ks], b, acc);
        }
    }
    __syncthreads();
    {
        int col = w * 16 + c;
        float ebv = eb2[col];
#pragma unroll
        for (int reg = 0; reg < 4; ++reg) {
            int r16 = q * 4 + reg, row = band + r16;
            float hval = acc[reg] + ebv;
            u16 hi, lo;
            split2(hval, hi, lo);
            h_hi[(size_t)row * HD + col] = hi;
            h_lo[(size_t)row * HD + col] = lo;
            int a = r16 * 128 + (((col >> 3) ^ r16) << 3) + (col & 7);
            tHi[a] = hi;
            tLo[a] = lo;
        }
    }
    __syncthreads();
#pragma unroll
    for (int ks = 0; ks < 4; ++ks) {
        int a = c * 128 + (((ks * 4 + q) ^ c) << 3);
        aH[ks] = *(const short8*)&tHi[a];
        aL[ks] = *(const short8*)&tLo[a];
    }
#pragma unroll
    for (int i = 0; i < 2; ++i) {
        int ctg = w * 2 + i;
        const u16* fb = fPQ0 + (size_t)ctg * 4 * 512 + lane * 8;
        f32x4 a3 = {0, 0, 0, 0};
#pragma unroll
        for (int ks = 0; ks < 4; ++ks) {
            short8 b = *(const short8*)(fb + ks * 512);
            a3 = MFMA(aH[ks], b, a3);
            a3 = MFMA(aL[ks], b, a3);
        }
        int col = ctg * 16 + c;
        if (ctg < 8) {
            float bias = mb1[col];
#pragma unroll
            for (int reg = 0; reg < 4; ++reg)
                PQf[(size_t)(band + q * 4 + reg) * HD + col] = a3[reg] + bias;
        } else {
            int colq = col - 128;
#pragma unroll
            for (int reg = 0; reg < 4; ++reg)
                Qb[(size_t)(band + q * 4 + reg) * HD + colq] = f2bf(a3[reg]);
        }
    }
}

// ---- k_gath: edge aggregation, interleaved chunk tasks.
// task = (node n, chunk ch in [0,NCH)); wave processes edges e = ch, ch+NCH, ...
// Every wave of a node gets ~deg/NCH edges (balanced). All <=16 bucket loads
// issued as a batch, then all <=16 Qb-row gathers, then accumulate (depth-16 MLP).
// Partial sums merged via 2 f32 atomicAdds/lane into S[n][128] (pre-zeroed).

__global__ __launch_bounds__(256) void k_gath(
    const float* __restrict__ PQf_in, const u16* __restrict__ Qb_in,
    const int* __restrict__ cnt, const float4* __restrict__ sea,
    const float* __restrict__ wc, float* __restrict__ S) {
    int w = threadIdx.x >> 6, lane = threadIdx.x & 63;
    int task = blockIdx.x * 4 + w;
    int n = task / NCH;
    int ch = task - n * NCH;
    if (n >= NN) return;
    int cn = cnt[n];
    int cle = cn < CAP ? cn : CAP;
    if (ch >= cle) return;
    int nm = (cle - ch + (NCH - 1)) / NCH;  // 1..16, wave-uniform
    int j = lane * 2;
    const float4* bk = sea + (size_t)n * CAP + ch;
    float2 p = *(const float2*)(PQf_in + (size_t)n * HD + j);
    float2 wcr0 = *(const float2*)(wc + j);
    float2 wcr1 = *(const float2*)(wc + HD + j);
    float2 wcr2 = *(const float2*)(wc + 2 * HD + j);
    float4 A[16];
    unsigned U[16];
#pragma unroll
    for (int k = 0; k < 16; ++k)
        if (k < nm) A[k] = bk[k * NCH];
#pragma unroll
    for (int k = 0; k < 16; ++k)
        if (k < nm) U[k] = *(const unsigned*)(Qb_in + (size_t)__float_as_uint(A[k].w) * HD + j);
    float acc0 = 0.f, acc1 = 0.f;
#pragma unroll
    for (int k = 0; k < 16; ++k)
        if (k < nm) {
            float c0 = A[k].x * wcr0.x + A[k].y * wcr1.x + A[k].z * wcr2.x;
            float c1 = A[k].x * wcr0.y + A[k].y * wcr1.y + A[k].z * wcr2.y;
            acc0 += fmaxf(p.x + __uint_as_float(U[k] << 16) + c0, 0.f);
            acc1 += fmaxf(p.y + __uint_as_float(U[k] & 0xffff0000u) + c1, 0.f);
        }
    atomicAdd(&S[(size_t)n * HD + j], acc0);
    atomicAdd(&S[(size_t)n * HD + j + 1], acc1);
}

// ------- fused layer (512 thr / 8 waves): S-stage -> G1 -> G2 -> LN -> (PQ next | dec) -----

template <bool LAST>
__global__ __launch_bounds__(512) void k_layer(
    const float* __restrict__ S, const int* __restrict__ cnt,
    u16* __restrict__ h_hi, u16* __restrict__ h_lo,
    const u16* __restrict__ fG1, const u16* __restrict__ fG2,
    const float* __restrict__ ub1, const float* __restrict__ c2l, const float* __restrict__ ub2,
    const float* __restrict__ g, const float* __restrict__ bb,
    const u16* __restrict__ fPQ, const float* __restrict__ nb1,
    float* __restrict__ PQf_out, u16* __restrict__ Qb_out,
    const u16* __restrict__ fDec, const float* __restrict__ db1, const float* __restrict__ dw2,
    const float* __restrict__ db2, float* __restrict__ out) {
    __shared__ u16 sHi[2048], sLo[2048];
    __shared__ u16 tHi[2048], tLo[2048];
    __shared__ float red[16][8][2];
    int tid = threadIdx.x, w = tid >> 6, lane = tid & 63, q = lane >> 4, c = lane & 15;
    int band = blockIdx.x * 16;
    int j = lane * 2;
    // ======== S staging: wave w handles rows w*2, w*2+1 ========
    {
#pragma unroll
        for (int i = 0; i < 2; ++i) {
            int r16 = w * 2 + i;
            int n = band + r16;
            int cn = cnt[n];
            float invn = 1.0f / fmaxf((float)cn, 1.0f);
            float2 s = *(const float2*)(S + (size_t)n * HD + j);
            float v0 = s.x * invn, v1 = s.y * invn;
            u16 h0, l0, h1, l1;
            split2(v0, h0, l0);
            split2(v1, h1, l1);
            int a = r16 * 128 + (((j >> 3) ^ r16) << 3) + (j & 7);
            *(ushort2*)&sHi[a] = make_ushort2(h0, h1);
            *(ushort2*)&sLo[a] = make_ushort2(l0, l1);
        }
    }
    __syncthreads();
    // ======== G1: A = [h (global) | S (LDS)], 1 ctg per wave ========
    short8 aH[8], aL[8];
    {
        size_t rb = (size_t)(band + c) * HD + q * 8;
#pragma unroll
        for (int ks = 0; ks < 4; ++ks) {
            aH[ks] = *(const short8*)(h_hi + rb + ks * 32);
            aL[ks] = *(const short8*)(h_lo + rb + ks * 32);
            int a = c * 128 + (((ks * 4 + q) ^ c) << 3);
            aH[4 + ks] = *(const short8*)&sHi[a];
            aL[4 + ks] = *(const short8*)&sLo[a];
        }
    }
    f32x4 acc = {0, 0, 0, 0};
    {
        const u16* fb = fG1 + (size_t)w * 8 * 512 + lane * 8;
#pragma unroll
        for (int ks = 0; ks < 8; ++ks) {
            short8 b = *(const short8*)(fb + ks * 512);
            acc = MFMA(aH[ks], b, acc);
            acc = MFMA(aL[ks], b, acc);
        }
    }
    float alv[4];
#pragma unroll
    for (int reg = 0; reg < 4; ++reg) alv[reg] = (cnt[band + q * 4 + reg] > 0) ? 1.f : 0.f;
    {
        int col = w * 16 + c;
        float u1b = ub1[col], cc = c2l[col];
#pragma unroll
        for (int reg = 0; reg < 4; ++reg) {
            int r16 = q * 4 + reg;
            float t = fmaxf(acc[reg] + u1b + alv[reg] * cc, 0.f);
            u16 hi, lo;
            split2(t, hi, lo);
            int a = r16 * 128 + (((col >> 3) ^ r16) << 3) + (col & 7);
            tHi[a] = hi;
            tLo[a] = lo;
        }
    }
    __syncthreads();
    // ======== G2: 1 ctg per wave ========
    short8 aH2[4], aL2[4];
#pragma unroll
    for (int ks = 0; ks < 4; ++ks) {
        int a = c * 128 + (((ks * 4 + q) ^ c) << 3);
        aH2[ks] = *(const short8*)&tHi[a];
        aL2[ks] = *(const short8*)&tLo[a];
    }
    f32x4 acc2 = {0, 0, 0, 0};
    {
        const u16* fb = fG2 + (size_t)w * 4 * 512 + lane * 8;
#pragma unroll
        for (int ks = 0; ks < 4; ++ks) {
            short8 b = *(const short8*)(fb + ks * 512);
            acc2 = MFMA(aH2[ks], b, acc2);
            acc2 = MFMA(aL2[ks], b, acc2);
        }
    }
    // ======== residual + LN ========
    float vv[4];
    {
        int col = w * 16 + c;
        float u2b = ub2[col];
#pragma unroll
        for (int reg = 0; reg < 4; ++reg) {
            size_t idx = (size_t)(band + q * 4 + reg) * HD + col;
            float hres = bf2f(h_hi[idx]) + bf2f(h_lo[idx]);
            vv[reg] = acc2[reg] + u2b + hres;
        }
    }
#pragma unroll
    for (int reg = 0; reg < 4; ++reg) {
        float s = vv[reg];
        float s2 = vv[reg] * vv[reg];
        for (int m = 1; m < 16; m <<= 1) {
            s += __shfl_xor(s, m);
            s2 += __shfl_xor(s2, m);
        }
        if (c == 0) {
            red[q * 4 + reg][w][0] = s;
            red[q * 4 + reg][w][1] = s2;
        }
    }
    __syncthreads();
    float mu[4], rs[4];
#pragma unroll
    for (int reg = 0; reg < 4; ++reg) {
        int r16 = q * 4 + reg;
        float S1 = 0.f, S2 = 0.f;
#pragma unroll
        for (int ww = 0; ww < 8; ++ww) {
            S1 += red[r16][ww][0];
            S2 += red[r16][ww][1];
        }
        float m = S1 * (1.f / HD);
        float var = S2 * (1.f / HD) - m * m;
        mu[reg] = m;
        rs[reg] = rsqrtf(var + LN_EPS);
    }
    {
        int col = w * 16 + c;
        float gg = g[col], bv = bb[col];
#pragma unroll
        for (int reg = 0; reg < 4; ++reg) {
            int r16 = q * 4 + reg;
            float o = (vv[reg] - mu[reg]) * rs[reg] * gg + bv;
            u16 hi, lo;
            split2(o, hi, lo);
            int a = r16 * 128 + (((col >> 3) ^ r16) << 3) + (col & 7);
            tHi[a] = hi;
            tLo[a] = lo;
            if (!LAST) {
                size_t idx = (size_t)(band + r16) * HD + col;
                h_hi[idx] = hi;
                h_lo[idx] = lo;
            }
        }
    }
    __syncthreads();
    short8 aH3[4], aL3[4];
#pragma unroll
    for (int ks = 0; ks < 4; ++ks) {
        int a = c * 128 + (((ks * 4 + q) ^ c) << 3);
        aH3[ks] = *(const short8*)&tHi[a];
        aL3[ks] = *(const short8*)&tLo[a];
    }
    if (!LAST) {
#pragma unroll
        for (int i = 0; i < 2; ++i) {
            int ctg = w * 2 + i;
            const u16* fb = fPQ + (size_t)ctg * 4 * 512 + lane * 8;
            f32x4 a3 = {0, 0, 0, 0};
#pragma unroll
            for (int ks = 0; ks < 4; ++ks) {
                short8 b = *(const short8*)(fb + ks * 512);
                a3 = MFMA(aH3[ks], b, a3);
                a3 = MFMA(aL3[ks], b, a3);
            }
            int col = ctg * 16 + c;
            if (ctg < 8) {
                float bias = nb1[col];
#pragma unroll
                for (int reg = 0; reg < 4; ++reg)
                    PQf_out[(size_t)(band + q * 4 + reg) * HD + col] = a3[reg] + bias;
            } else {
                int colq = col - 128;
#pragma unroll
                for (int reg = 0; reg < 4; ++reg)
                    Qb_out[(size_t)(band + q * 4 + reg) * HD + colq] = f2bf(a3[reg]);
            }
        }
    } else {
        float part[4];
        {
            const u16* fb = fDec + (size_t)w * 4 * 512 + lane * 8;
            f32x4 a3 = {0, 0, 0, 0};
#pragma unroll
            for (int ks = 0; ks < 4; ++ks) {
                short8 b = *(const short8*)(fb + ks * 512);
                a3 = MFMA(aH3[ks], b, a3);
                a3 = MFMA(aL3[ks], b, a3);
            }
            int col = w * 16 + c;
            float w2v = dw2[col], b1v = db1[col];
#pragma unroll
            for (int reg = 0; reg < 4; ++reg) part[reg] = fmaxf(a3[reg] + b1v, 0.f) * w2v;
        }
#pragma unroll
        for (int reg = 0; reg < 4; ++reg) {
            float s = part[reg];
            for (int m = 1; m < 16; m <<= 1) s += __shfl_xor(s, m);
            if (c == 0) red[q * 4 + reg][w][0] = s;
        }
        __syncthreads();
        if (tid < 16) {
            float s = db2[0];
#pragma unroll
            for (int ww = 0; ww < 8; ++ww) s += red[tid][ww][0];
            out[band + tid] = s;
        }
    }
}

// ---------------- launch ----------------

extern "C" void kernel_launch(void* const* d_in, const int* in_sizes, int n_in,
                              void* d_out, int out_size, void* d_ws, size_t ws_size,
                              hipStream_t stream) {
    const float* x = (const float*)d_in[0];
    const int* eidx = (const int*)d_in[1];
    const float* eattr = (const float*)d_in[2];
    const float* enc_w1 = (const float*)d_in[3];
    const float* enc_b1 = (const float*)d_in[4];
    const float* enc_w2 = (const float*)d_in[5];
    const float* enc_b2 = (const float*)d_in[6];
    const float* msg_w1 = (const float*)d_in[7];
    const float* msg_b1 = (const float*)d_in[8];
    const float* msg_w2 = (const float*)d_in[9];
    const float* msg_b2 = (const float*)d_in[10];
    const float* upd_w1 = (const float*)d_in[11];
    const float* upd_b1 = (const float*)d_in[12];
    const float* upd_w2 = (const float*)d_in[13];
    const float* upd_b2 = (const float*)d_in[14];
    const float* ln_g = (const float*)d_in[15];
    const float* ln_b = (const float*)d_in[16];
    const float* dec_w1 = (const float*)d_in[17];
    const float* dec_b1 = (const float*)d_in[18];
    const float* dec_w2 = (const float*)d_in[19];
    const float* dec_b2 = (const float*)d_in[20];
    const int* srcp = eidx;
    const int* tgtp = eidx + NE;

    char* base = (char*)d_ws;
    size_t off = 0;
    auto alloc = [&](size_t bytes) -> void* {
        off = (off + 15) & ~(size_t)15;
        void* p = base + off;
        off += bytes;
        return p;
    };
    float4* sea = (float4*)alloc((size_t)NN * CAP * 16);
    float* PQf0 = (float*)alloc((size_t)NN * HD * 4);
    float* PQf1 = (float*)alloc((size_t)NN * HD * 4);
    u16* Qb0 = (u16*)alloc((size_t)NN * HD * 2);
    u16* Qb1 = (u16*)alloc((size_t)NN * HD * 2);
    u16* h_hi = (u16*)alloc((size_t)NN * HD * 2);
    u16* h_lo = (u16*)alloc((size_t)NN * HD * 2);
    int* cnt = (int*)alloc((size_t)NN * 4);
    float* c2 = (float*)alloc((size_t)NL * HD * 4);
    u16* fG1 = (u16*)alloc((size_t)131072 * 2);
    u16* fG2 = (u16*)alloc((size_t)65536 * 2);
    u16* fPQ = (u16*)alloc((size_t)131072 * 2);
    u16* fDec = (u16*)alloc((size_t)16384 * 2);
    u16* fEnc = (u16*)alloc((size_t)16384 * 2);
    float* Sbuf = (float*)alloc((size_t)NL * NN * HD * 4);

    hipMemsetAsync(cnt, 0, (size_t)NN * 4, stream);
    hipMemsetAsync(Sbuf, 0, (size_t)NL * NN * HD * 4, stream);
    k_prepscat<<<442 + (NE + 255) / 256, 256, 0, stream>>>(
        msg_w2, msg_b2, upd_w1, upd_w2, msg_w1, dec_w1, enc_w2,
        c2, fG1, fG2, fPQ, fDec, fEnc,
        srcp, tgtp, eattr, cnt, sea);
    k_enc<<<625, 512, 0, stream>>>(x, enc_w1, enc_b1, fEnc, enc_b2, fPQ,
                                   msg_b1, h_hi, h_lo, PQf0, Qb0);

    float* PQin = PQf0;
    u16* Qin = Qb0;
    float* PQout = PQf1;
    u16* Qout = Qb1;
    const int gath_blocks = (NN * NCH + 3) / 4;
    for (int l = 0; l < NL; ++l) {
        const float* wc = msg_w1 + (size_t)l * (2 * HD + EDIM) * HD + (size_t)2 * HD * HD;
        float* Sl = Sbuf + (size_t)l * NN * HD;
        k_gath<<<gath_blocks, 256, 0, stream>>>(PQin, Qin, cnt, sea, wc, Sl);
        if (l < NL - 1) {
            k_layer<false><<<NN / 16, 512, 0, stream>>>(
                Sl, cnt, h_hi, h_lo,
                fG1 + (size_t)l * 32768, fG2 + (size_t)l * 16384,
                upd_b1 + l * HD, c2 + l * HD, upd_b2 + l * HD, ln_g + l * HD, ln_b + l * HD,
                fPQ + (size_t)(l + 1) * 32768, msg_b1 + (size_t)(l + 1) * HD, PQout, Qout,
                nullptr, nullptr, nullptr, nullptr, nullptr);
        } else {
            k_layer<true><<<NN / 16, 512, 0, stream>>>(
                Sl, cnt, h_hi, h_lo,
                fG1 + (size_t)l * 32768, fG2 + (size_t)l * 16384,
                upd_b1 + l * HD, c2 + l * HD, upd_b2 + l * HD, ln_g + l * HD, ln_b + l * HD,
                nullptr, nullptr, nullptr, nullptr,
                fDec, dec_b1, dec_w2, dec_b2, (float*)d_out);
        }
        float* tf = PQin; PQin = PQout; PQout = tf;
        u16* tq = Qin; Qin = Qout; Qout = tq;
    }
}

// Round 4
// 498.865 us; speedup vs baseline: 1.0211x; 1.0211x over previous
//
#include <hip/hip_runtime.h>

#define NN 10000
#define NE 400000
#define HD 128
#define NIN 6
#define EDIM 3
#define NL 4
#define CAP 96
#define NCH 8
#define LN_EPS 1e-5f

typedef unsigned short u16;
using short8 = __attribute__((ext_vector_type(8))) short;
using f32x4 = __attribute__((ext_vector_type(4))) float;

__device__ __forceinline__ u16 f2bf(float x) {
    unsigned u = __float_as_uint(x);
    return (u16)((u + 0x7fff + ((u >> 16) & 1)) >> 16);
}
__device__ __forceinline__ float bf2f(u16 h) { return __uint_as_float(((unsigned)h) << 16); }
__device__ __forceinline__ void split2(float x, u16& hi, u16& lo) {
    hi = f2bf(x);
    lo = f2bf(x - bf2f(hi));
}
#define MFMA(a, b, c) __builtin_amdgcn_mfma_f32_16x16x32_bf16((a), (b), (c), 0, 0, 0)

// ---- k_prepscat: weight prep (blocks [0,442)) + edge scatter (blocks [442,...)).
// cnt zeroed by hipMemsetAsync before this kernel.

__global__ __launch_bounds__(256) void k_prepscat(
    const float* __restrict__ msg_w2, const float* __restrict__ msg_b2, const float* __restrict__ upd_w1,
    const float* __restrict__ upd_w2, const float* __restrict__ msg_w1, const float* __restrict__ dec_w1,
    const float* __restrict__ enc_w2, float* __restrict__ c2,
    u16* __restrict__ fG1, u16* __restrict__ fG2, u16* __restrict__ fPQ,
    u16* __restrict__ fDec, u16* __restrict__ fEnc,
    const int* __restrict__ srcp, const int* __restrict__ tgtp, const float* __restrict__ eattr,
    int* __restrict__ cnt, float4* __restrict__ sea) {
    if (blockIdx.x >= 442) {
        int e = (blockIdx.x - 442) * 256 + threadIdx.x;
        if (e < NE) {
            int t = tgtp[e];
            int pos = atomicAdd(&cnt[t], 1);
            if (pos < CAP) {
                sea[t * CAP + pos] = make_float4(eattr[e * 3], eattr[e * 3 + 1], eattr[e * 3 + 2],
                                                 __uint_as_float((unsigned)srcp[e]));
            }
        }
        return;
    }
    int idx = blockIdx.x * 256 + threadIdx.x;
    if (idx < 65536) {
        int l = idx >> 14, rem = idx & 16383, i = rem >> 7, jj = rem & 127;
        const float* U1b = upd_w1 + (size_t)l * 2 * HD * HD + (size_t)HD * HD;
        const float* W2 = msg_w2 + (size_t)l * HD * HD + (size_t)i * HD;
        float acc = 0.f;
        for (int t = 0; t < HD; ++t) acc += W2[t] * U1b[(size_t)t * HD + jj];
        int ct = jj >> 4;
        int ks = 4 + (i >> 5);
        int lane = (((i & 31) >> 3) << 4) | (jj & 15);
        int j = i & 7;
        int g = (l << 12) | (ct << 9) | (ks << 6) | lane;
        fG1[(size_t)g * 8 + j] = f2bf(acc);
    } else if (idx < 66048) {
        int r = idx - 65536;
        int l = r >> 7, jj = r & 127;
        const float* U1b = upd_w1 + (size_t)l * 2 * HD * HD + (size_t)HD * HD;
        const float* b2 = msg_b2 + l * HD;
        float acc = 0.f;
        for (int t = 0; t < HD; ++t) acc += b2[t] * U1b[(size_t)t * HD + jj];
        c2[r] = acc;
    } else if (idx < 76048) {
        // dead
    } else if (idx < 84240) {
        int gl = idx - 76048;
        int l = gl >> 11, rem = gl & 2047;
        int ct = rem >> 8, ks = (rem >> 6) & 3, lane = rem & 63;
        int n = ct * 16 + (lane & 15), kb = ks * 32 + ((lane >> 4) << 3);
        int g = (l << 12) | (ct << 9) | (ks << 6) | lane;
        u16* dst = fG1 + (size_t)g * 8;
        const float* U = upd_w1 + (size_t)l * 256 * 128;
#pragma unroll
        for (int j = 0; j < 8; ++j) dst[j] = f2bf(U[(size_t)(kb + j) * 128 + n]);
    } else if (idx < 92432) {
        int gg = idx - 84240;
        int l = gg >> 11, r = gg & 2047;
        int ct = r >> 8, ks = (r >> 6) & 3, lane = r & 63;
        int n = ct * 16 + (lane & 15), kb = ks * 32 + ((lane >> 4) << 3);
        u16* dst = fG2 + (size_t)gg * 8;
        const float* W = upd_w2 + (size_t)l * 128 * 128;
#pragma unroll
        for (int j = 0; j < 8; ++j) dst[j] = f2bf(W[(size_t)(kb + j) * 128 + n]);
    } else if (idx < 108816) {
        int gg = idx - 92432;
        int li = gg >> 12, r = gg & 4095;
        int ct = r >> 8, ks = (r >> 6) & 3, lane = r & 63;
        int n = ct * 16 + (lane & 15), kb = ks * 32 + ((lane >> 4) << 3);
        u16* dst = fPQ + (size_t)gg * 8;
        const float* W = msg_w1 + (size_t)li * (2 * HD + EDIM) * HD;
#pragma unroll
        for (int j = 0; j < 8; ++j) {
            int k = kb + j;
            float v = (n < 128) ? W[(size_t)k * 128 + n] : W[(size_t)(128 + k) * 128 + (n - 128)];
            dst[j] = f2bf(v);
        }
    } else if (idx < 110864) {
        int r = idx - 108816;
        int ct = r >> 8, ks = (r >> 6) & 3, lane = r & 63;
        int n = ct * 16 + (lane & 15), kb = ks * 32 + ((lane >> 4) << 3);
        u16* dst = fDec + (size_t)r * 8;
#pragma unroll
        for (int j = 0; j < 8; ++j) dst[j] = f2bf(dec_w1[(size_t)(kb + j) * 128 + n]);
    } else if (idx < 112912) {
        int r = idx - 110864;
        int ct = r >> 8, ks = (r >> 6) & 3, lane = r & 63;
        int n = ct * 16 + (lane & 15), kb = ks * 32 + ((lane >> 4) << 3);
        u16* dst = fEnc + (size_t)r * 8;
#pragma unroll
        for (int j = 0; j < 8; ++j) dst[j] = f2bf(enc_w2[(size_t)(kb + j) * 128 + n]);
    }
}

// ---- k_enc: encoder (16 nodes per block) + PQ0 precompute ----

__global__ __launch_bounds__(512) void k_enc(
    const float* __restrict__ x, const float* __restrict__ ew1, const float* __restrict__ eb1,
    const u16* __restrict__ fEnc, const float* __restrict__ eb2, const u16* __restrict__ fPQ0,
    const float* __restrict__ mb1, u16* __restrict__ h_hi, u16* __restrict__ h_lo,
    float* __restrict__ PQf, u16* __restrict__ Qb) {
    __shared__ u16 tHi[2048], tLo[2048];
    int tid = threadIdx.x, w = tid >> 6, lane = tid & 63, q = lane >> 4, c = lane & 15;
    int band = blockIdx.x * 16;
    {
        int col = w * 16 + c;
        float wv[NIN];
#pragma unroll
        for (int k = 0; k < NIN; ++k) wv[k] = ew1[k * HD + col];
        float ebv = eb1[col];
#pragma unroll
        for (int reg = 0; reg < 4; ++reg) {
            int row = band + q * 4 + reg;
            float t = ebv;
#pragma unroll
            for (int k = 0; k < NIN; ++k) t += x[(size_t)row * NIN + k] * wv[k];
            t = fmaxf(t, 0.f);
            u16 hi, lo;
            split2(t, hi, lo);
            int r16 = q * 4 + reg;
            int a = r16 * 128 + (((col >> 3) ^ r16) << 3) + (col & 7);
            tHi[a] = hi;
            tLo[a] = lo;
        }
    }
    __syncthreads();
    short8 aH[4], aL[4];
#pragma unroll
    for (int ks = 0; ks < 4; ++ks) {
        int a = c * 128 + (((ks * 4 + q) ^ c) << 3);
        aH[ks] = *(const short8*)&tHi[a];
        aL[ks] = *(const short8*)&tLo[a];
    }
    f32x4 acc = {0, 0, 0, 0};
    {
        const u16* fb = fEnc + (size_t)w * 4 * 512 + lane * 8;
#pragma unroll
        for (int ks = 0; ks < 4; ++ks) {
            short8 b = *(const short8*)(fb + ks * 512);
            acc = MFMA(aH[ks], b, acc);
            acc = MFMA(aL[ks], b, acc);
        }
    }
    __syncthreads();
    {
        int col = w * 16 + c;
        float ebv = eb2[col];
#pragma unroll
        for (int reg = 0; reg < 4; ++reg) {
            int r16 = q * 4 + reg, row = band + r16;
            float hval = acc[reg] + ebv;
            u16 hi, lo;
            split2(hval, hi, lo);
            h_hi[(size_t)row * HD + col] = hi;
            h_lo[(size_t)row * HD + col] = lo;
            int a = r16 * 128 + (((col >> 3) ^ r16) << 3) + (col & 7);
            tHi[a] = hi;
            tLo[a] = lo;
        }
    }
    __syncthreads();
#pragma unroll
    for (int ks = 0; ks < 4; ++ks) {
        int a = c * 128 + (((ks * 4 + q) ^ c) << 3);
        aH[ks] = *(const short8*)&tHi[a];
        aL[ks] = *(const short8*)&tLo[a];
    }
#pragma unroll
    for (int i = 0; i < 2; ++i) {
        int ctg = w * 2 + i;
        const u16* fb = fPQ0 + (size_t)ctg * 4 * 512 + lane * 8;
        f32x4 a3 = {0, 0, 0, 0};
#pragma unroll
        for (int ks = 0; ks < 4; ++ks) {
            short8 b = *(const short8*)(fb + ks * 512);
            a3 = MFMA(aH[ks], b, a3);
            a3 = MFMA(aL[ks], b, a3);
        }
        int col = ctg * 16 + c;
        if (ctg < 8) {
            float bias = mb1[col];
#pragma unroll
            for (int reg = 0; reg < 4; ++reg)
                PQf[(size_t)(band + q * 4 + reg) * HD + col] = a3[reg] + bias;
        } else {
            int colq = col - 128;
#pragma unroll
            for (int reg = 0; reg < 4; ++reg)
                Qb[(size_t)(band + q * 4 + reg) * HD + colq] = f2bf(a3[reg]);
        }
    }
}

// ---- k_gath: edge aggregation. Block = node (8 waves). Wave w takes edges
// e = w, w+8, w+16, ... (<=12 at CAP=96); all bucket loads batched, then all
// Qb row gathers batched (depth-12 MLP). Partials merged in LDS (deterministic),
// then 128 threads apply 1/deg + split2 and write bf16 hi/lo aggregate rows
// (same layout as h_hi/h_lo, so k_layer loads them directly as G1 fragments).

__global__ __launch_bounds__(512) void k_gath(
    const float* __restrict__ PQf_in, const u16* __restrict__ Qb_in,
    const int* __restrict__ cnt, const float4* __restrict__ sea,
    const float* __restrict__ wc, u16* __restrict__ agg_hi, u16* __restrict__ agg_lo) {
    __shared__ float part[NCH][HD];
    int tid = threadIdx.x, w = tid >> 6, lane = tid & 63;
    int n = blockIdx.x;
    int cn = cnt[n];
    int cle = cn < CAP ? cn : CAP;
    int j = lane * 2;
    float acc0 = 0.f, acc1 = 0.f;
    int nm = (cle > w) ? ((cle - w + (NCH - 1)) / NCH) : 0;  // 0..12, wave-uniform
    if (nm) {
        const float4* bk = sea + (size_t)n * CAP + w;
        float2 p = *(const float2*)(PQf_in + (size_t)n * HD + j);
        float2 wcr0 = *(const float2*)(wc + j);
        float2 wcr1 = *(const float2*)(wc + HD + j);
        float2 wcr2 = *(const float2*)(wc + 2 * HD + j);
        float4 A[12];
        unsigned U[12];
#pragma unroll
        for (int k = 0; k < 12; ++k)
            if (k < nm) A[k] = bk[k * NCH];
#pragma unroll
        for (int k = 0; k < 12; ++k)
            if (k < nm) U[k] = *(const unsigned*)(Qb_in + (size_t)__float_as_uint(A[k].w) * HD + j);
#pragma unroll
        for (int k = 0; k < 12; ++k)
            if (k < nm) {
                float c0 = A[k].x * wcr0.x + A[k].y * wcr1.x + A[k].z * wcr2.x;
                float c1 = A[k].x * wcr0.y + A[k].y * wcr1.y + A[k].z * wcr2.y;
                acc0 += fmaxf(p.x + __uint_as_float(U[k] << 16) + c0, 0.f);
                acc1 += fmaxf(p.y + __uint_as_float(U[k] & 0xffff0000u) + c1, 0.f);
            }
    }
    part[w][j] = acc0;
    part[w][j + 1] = acc1;
    __syncthreads();
    if (tid < HD) {
        float s = 0.f;
#pragma unroll
        for (int ww = 0; ww < NCH; ++ww) s += part[ww][tid];
        float invn = 1.0f / fmaxf((float)cn, 1.0f);
        float v = s * invn;
        u16 hi, lo;
        split2(v, hi, lo);
        agg_hi[(size_t)n * HD + tid] = hi;
        agg_lo[(size_t)n * HD + tid] = lo;
    }
}

// ------- fused layer (512 thr / 8 waves): G1 -> G2 -> LN -> (PQ next | dec) -----
// A-fragments for G1: rows k<128 from h_hi/h_lo, k>=128 from agg_hi/agg_lo (global).

template <bool LAST>
__global__ __launch_bounds__(512) void k_layer(
    const u16* __restrict__ agg_hi, const u16* __restrict__ agg_lo, const int* __restrict__ cnt,
    u16* __restrict__ h_hi, u16* __restrict__ h_lo,
    const u16* __restrict__ fG1, const u16* __restrict__ fG2,
    const float* __restrict__ ub1, const float* __restrict__ c2l, const float* __restrict__ ub2,
    const float* __restrict__ g, const float* __restrict__ bb,
    const u16* __restrict__ fPQ, const float* __restrict__ nb1,
    float* __restrict__ PQf_out, u16* __restrict__ Qb_out,
    const u16* __restrict__ fDec, const float* __restrict__ db1, const float* __restrict__ dw2,
    const float* __restrict__ db2, float* __restrict__ out) {
    __shared__ u16 tHi[2048], tLo[2048];
    __shared__ float red[16][8][2];
    int tid = threadIdx.x, w = tid >> 6, lane = tid & 63, q = lane >> 4, c = lane & 15;
    int band = blockIdx.x * 16;
    // ======== G1: A = [h | agg] straight from global, 1 ctg per wave ========
    short8 aH[8], aL[8];
    {
        size_t rb = (size_t)(band + c) * HD + q * 8;
#pragma unroll
        for (int ks = 0; ks < 4; ++ks) {
            aH[ks] = *(const short8*)(h_hi + rb + ks * 32);
            aL[ks] = *(const short8*)(h_lo + rb + ks * 32);
            aH[4 + ks] = *(const short8*)(agg_hi + rb + ks * 32);
            aL[4 + ks] = *(const short8*)(agg_lo + rb + ks * 32);
        }
    }
    f32x4 acc = {0, 0, 0, 0};
    {
        const u16* fb = fG1 + (size_t)w * 8 * 512 + lane * 8;
#pragma unroll
        for (int ks = 0; ks < 8; ++ks) {
            short8 b = *(const short8*)(fb + ks * 512);
            acc = MFMA(aH[ks], b, acc);
            acc = MFMA(aL[ks], b, acc);
        }
    }
    float alv[4];
#pragma unroll
    for (int reg = 0; reg < 4; ++reg) alv[reg] = (cnt[band + q * 4 + reg] > 0) ? 1.f : 0.f;
    {
        int col = w * 16 + c;
        float u1b = ub1[col], cc = c2l[col];
#pragma unroll
        for (int reg = 0; reg < 4; ++reg) {
            int r16 = q * 4 + reg;
            float t = fmaxf(acc[reg] + u1b + alv[reg] * cc, 0.f);
            u16 hi, lo;
            split2(t, hi, lo);
            int a = r16 * 128 + (((col >> 3) ^ r16) << 3) + (col & 7);
            tHi[a] = hi;
            tLo[a] = lo;
        }
    }
    __syncthreads();
    // ======== G2: 1 ctg per wave ========
    short8 aH2[4], aL2[4];
#pragma unroll
    for (int ks = 0; ks < 4; ++ks) {
        int a = c * 128 + (((ks * 4 + q) ^ c) << 3);
        aH2[ks] = *(const short8*)&tHi[a];
        aL2[ks] = *(const short8*)&tLo[a];
    }
    f32x4 acc2 = {0, 0, 0, 0};
    {
        const u16* fb = fG2 + (size_t)w * 4 * 512 + lane * 8;
#pragma unroll
        for (int ks = 0; ks < 4; ++ks) {
            short8 b = *(const short8*)(fb + ks * 512);
            acc2 = MFMA(aH2[ks], b, acc2);
            acc2 = MFMA(aL2[ks], b, acc2);
        }
    }
    // ======== residual + LN ========
    float vv[4];
    {
        int col = w * 16 + c;
        float u2b = ub2[col];
#pragma unroll
        for (int reg = 0; reg < 4; ++reg) {
            size_t idx = (size_t)(band + q * 4 + reg) * HD + col;
            float hres = bf2f(h_hi[idx]) + bf2f(h_lo[idx]);
            vv[reg] = acc2[reg] + u2b + hres;
        }
    }
#pragma unroll
    for (int reg = 0; reg < 4; ++reg) {
        float s = vv[reg];
        float s2 = vv[reg] * vv[reg];
        for (int m = 1; m < 16; m <<= 1) {
            s += __shfl_xor(s, m);
            s2 += __shfl_xor(s2, m);
        }
        if (c == 0) {
            red[q * 4 + reg][w][0] = s;
            red[q * 4 + reg][w][1] = s2;
        }
    }
    __syncthreads();
    float mu[4], rs[4];
#pragma unroll
    for (int reg = 0; reg < 4; ++reg) {
        int r16 = q * 4 + reg;
        float S1 = 0.f, S2 = 0.f;
#pragma unroll
        for (int ww = 0; ww < 8; ++ww) {
            S1 += red[r16][ww][0];
            S2 += red[r16][ww][1];
        }
        float m = S1 * (1.f / HD);
        float var = S2 * (1.f / HD) - m * m;
        mu[reg] = m;
        rs[reg] = rsqrtf(var + LN_EPS);
    }
    {
        int col = w * 16 + c;
        float gg = g[col], bv = bb[col];
#pragma unroll
        for (int reg = 0; reg < 4; ++reg) {
            int r16 = q * 4 + reg;
            float o = (vv[reg] - mu[reg]) * rs[reg] * gg + bv;
            u16 hi, lo;
            split2(o, hi, lo);
            int a = r16 * 128 + (((col >> 3) ^ r16) << 3) + (col & 7);
            tHi[a] = hi;
            tLo[a] = lo;
            if (!LAST) {
                size_t idx = (size_t)(band + r16) * HD + col;
                h_hi[idx] = hi;
                h_lo[idx] = lo;
            }
        }
    }
    __syncthreads();
    short8 aH3[4], aL3[4];
#pragma unroll
    for (int ks = 0; ks < 4; ++ks) {
        int a = c * 128 + (((ks * 4 + q) ^ c) << 3);
        aH3[ks] = *(const short8*)&tHi[a];
        aL3[ks] = *(const short8*)&tLo[a];
    }
    if (!LAST) {
#pragma unroll
        for (int i = 0; i < 2; ++i) {
            int ctg = w * 2 + i;
            const u16* fb = fPQ + (size_t)ctg * 4 * 512 + lane * 8;
            f32x4 a3 = {0, 0, 0, 0};
#pragma unroll
            for (int ks = 0; ks < 4; ++ks) {
                short8 b = *(const short8*)(fb + ks * 512);
                a3 = MFMA(aH3[ks], b, a3);
                a3 = MFMA(aL3[ks], b, a3);
            }
            int col = ctg * 16 + c;
            if (ctg < 8) {
                float bias = nb1[col];
#pragma unroll
                for (int reg = 0; reg < 4; ++reg)
                    PQf_out[(size_t)(band + q * 4 + reg) * HD + col] = a3[reg] + bias;
            } else {
                int colq = col - 128;
#pragma unroll
                for (int reg = 0; reg < 4; ++reg)
                    Qb_out[(size_t)(band + q * 4 + reg) * HD + colq] = f2bf(a3[reg]);
            }
        }
    } else {
        float part[4];
        {
            const u16* fb = fDec + (size_t)w * 4 * 512 + lane * 8;
            f32x4 a3 = {0, 0, 0, 0};
#pragma unroll
            for (int ks = 0; ks < 4; ++ks) {
                short8 b = *(const short8*)(fb + ks * 512);
                a3 = MFMA(aH3[ks], b, a3);
                a3 = MFMA(aL3[ks], b, a3);
            }
            int col = w * 16 + c;
            float w2v = dw2[col], b1v = db1[col];
#pragma unroll
            for (int reg = 0; reg < 4; ++reg) part[reg] = fmaxf(a3[reg] + b1v, 0.f) * w2v;
        }
#pragma unroll
        for (int reg = 0; reg < 4; ++reg) {
            float s = part[reg];
            for (int m = 1; m < 16; m <<= 1) s += __shfl_xor(s, m);
            if (c == 0) red[q * 4 + reg][w][0] = s;
        }
        __syncthreads();
        if (tid < 16) {
            float s = db2[0];
#pragma unroll
            for (int ww = 0; ww < 8; ++ww) s += red[tid][ww][0];
            out[band + tid] = s;
        }
    }
}

// ---------------- launch ----------------

extern "C" void kernel_launch(void* const* d_in, const int* in_sizes, int n_in,
                              void* d_out, int out_size, void* d_ws, size_t ws_size,
                              hipStream_t stream) {
    const float* x = (const float*)d_in[0];
    const int* eidx = (const int*)d_in[1];
    const float* eattr = (const float*)d_in[2];
    const float* enc_w1 = (const float*)d_in[3];
    const float* enc_b1 = (const float*)d_in[4];
    const float* enc_w2 = (const float*)d_in[5];
    const float* enc_b2 = (const float*)d_in[6];
    const float* msg_w1 = (const float*)d_in[7];
    const float* msg_b1 = (const float*)d_in[8];
    const float* msg_w2 = (const float*)d_in[9];
    const float* msg_b2 = (const float*)d_in[10];
    const float* upd_w1 = (const float*)d_in[11];
    const float* upd_b1 = (const float*)d_in[12];
    const float* upd_w2 = (const float*)d_in[13];
    const float* upd_b2 = (const float*)d_in[14];
    const float* ln_g = (const float*)d_in[15];
    const float* ln_b = (const float*)d_in[16];
    const float* dec_w1 = (const float*)d_in[17];
    const float* dec_b1 = (const float*)d_in[18];
    const float* dec_w2 = (const float*)d_in[19];
    const float* dec_b2 = (const float*)d_in[20];
    const int* srcp = eidx;
    const int* tgtp = eidx + NE;

    char* base = (char*)d_ws;
    size_t off = 0;
    auto alloc = [&](size_t bytes) -> void* {
        off = (off + 15) & ~(size_t)15;
        void* p = base + off;
        off += bytes;
        return p;
    };
    float4* sea = (float4*)alloc((size_t)NN * CAP * 16);
    float* PQf0 = (float*)alloc((size_t)NN * HD * 4);
    float* PQf1 = (float*)alloc((size_t)NN * HD * 4);
    u16* Qb0 = (u16*)alloc((size_t)NN * HD * 2);
    u16* Qb1 = (u16*)alloc((size_t)NN * HD * 2);
    u16* h_hi = (u16*)alloc((size_t)NN * HD * 2);
    u16* h_lo = (u16*)alloc((size_t)NN * HD * 2);
    u16* agg_hi = (u16*)alloc((size_t)NN * HD * 2);
    u16* agg_lo = (u16*)alloc((size_t)NN * HD * 2);
    int* cnt = (int*)alloc((size_t)NN * 4);
    float* c2 = (float*)alloc((size_t)NL * HD * 4);
    u16* fG1 = (u16*)alloc((size_t)131072 * 2);
    u16* fG2 = (u16*)alloc((size_t)65536 * 2);
    u16* fPQ = (u16*)alloc((size_t)131072 * 2);
    u16* fDec = (u16*)alloc((size_t)16384 * 2);
    u16* fEnc = (u16*)alloc((size_t)16384 * 2);

    hipMemsetAsync(cnt, 0, (size_t)NN * 4, stream);
    k_prepscat<<<442 + (NE + 255) / 256, 256, 0, stream>>>(
        msg_w2, msg_b2, upd_w1, upd_w2, msg_w1, dec_w1, enc_w2,
        c2, fG1, fG2, fPQ, fDec, fEnc,
        srcp, tgtp, eattr, cnt, sea);
    k_enc<<<625, 512, 0, stream>>>(x, enc_w1, enc_b1, fEnc, enc_b2, fPQ,
                                   msg_b1, h_hi, h_lo, PQf0, Qb0);

    float* PQin = PQf0;
    u16* Qin = Qb0;
    float* PQout = PQf1;
    u16* Qout = Qb1;
    for (int l = 0; l < NL; ++l) {
        const float* wc = msg_w1 + (size_t)l * (2 * HD + EDIM) * HD + (size_t)2 * HD * HD;
        k_gath<<<NN, 512, 0, stream>>>(PQin, Qin, cnt, sea, wc, agg_hi, agg_lo);
        if (l < NL - 1) {
            k_layer<false><<<NN / 16, 512, 0, stream>>>(
                agg_hi, agg_lo, cnt, h_hi, h_lo,
                fG1 + (size_t)l * 32768, fG2 + (size_t)l * 16384,
                upd_b1 + l * HD, c2 + l * HD, upd_b2 + l * HD, ln_g + l * HD, ln_b + l * HD,
                fPQ + (size_t)(l + 1) * 32768, msg_b1 + (size_t)(l + 1) * HD, PQout, Qout,
                nullptr, nullptr, nullptr, nullptr, nullptr);
        } else {
            k_layer<true><<<NN / 16, 512, 0, stream>>>(
                agg_hi, agg_lo, cnt, h_hi, h_lo,
                fG1 + (size_t)l * 32768, fG2 + (size_t)l * 16384,
                upd_b1 + l * HD, c2 + l * HD, upd_b2 + l * HD, ln_g + l * HD, ln_b + l * HD,
                nullptr, nullptr, nullptr, nullptr,
                fDec, dec_b1, dec_w2, dec_b2, (float*)d_out);
        }
        float* tf = PQin; PQin = PQout; PQout = tf;
        u16* tq = Qin; Qin = Qout; Qout = tq;
    }
}

// Round 5
// 307.860 us; speedup vs baseline: 1.6547x; 1.6204x over previous
//
#include <hip/hip_runtime.h>

#define NN 10000
#define NE 400000
#define HD 128
#define NIN 6
#define EDIM 3
#define NL 4
#define CAP 96
#define LN_EPS 1e-5f

typedef unsigned short u16;
using short8 = __attribute__((ext_vector_type(8))) short;
using f32x4 = __attribute__((ext_vector_type(4))) float;

__device__ __forceinline__ u16 f2bf(float x) {
    unsigned u = __float_as_uint(x);
    return (u16)((u + 0x7fff + ((u >> 16) & 1)) >> 16);
}
__device__ __forceinline__ float bf2f(u16 h) { return __uint_as_float(((unsigned)h) << 16); }
__device__ __forceinline__ void split2(float x, u16& hi, u16& lo) {
    hi = f2bf(x);
    lo = f2bf(x - bf2f(hi));
}
#define MFMA(a, b, c) __builtin_amdgcn_mfma_f32_16x16x32_bf16((a), (b), (c), 0, 0, 0)

// ---- k_prepscat: weight prep (blocks [0,442)) + edge scatter (blocks [442,...)).
// cnt zeroed by hipMemsetAsync before this kernel.

__global__ __launch_bounds__(256) void k_prepscat(
    const float* __restrict__ msg_w2, const float* __restrict__ msg_b2, const float* __restrict__ upd_w1,
    const float* __restrict__ upd_w2, const float* __restrict__ msg_w1, const float* __restrict__ dec_w1,
    const float* __restrict__ enc_w2, float* __restrict__ c2,
    u16* __restrict__ fG1, u16* __restrict__ fG2, u16* __restrict__ fPQ,
    u16* __restrict__ fDec, u16* __restrict__ fEnc,
    const int* __restrict__ srcp, const int* __restrict__ tgtp, const float* __restrict__ eattr,
    int* __restrict__ cnt, float4* __restrict__ sea) {
    if (blockIdx.x >= 442) {
        int e = (blockIdx.x - 442) * 256 + threadIdx.x;
        if (e < NE) {
            int t = tgtp[e];
            int pos = atomicAdd(&cnt[t], 1);
            if (pos < CAP) {
                sea[t * CAP + pos] = make_float4(eattr[e * 3], eattr[e * 3 + 1], eattr[e * 3 + 2],
                                                 __uint_as_float((unsigned)srcp[e]));
            }
        }
        return;
    }
    int idx = blockIdx.x * 256 + threadIdx.x;
    if (idx < 65536) {
        int l = idx >> 14, rem = idx & 16383, i = rem >> 7, jj = rem & 127;
        const float* U1b = upd_w1 + (size_t)l * 2 * HD * HD + (size_t)HD * HD;
        const float* W2 = msg_w2 + (size_t)l * HD * HD + (size_t)i * HD;
        float acc = 0.f;
        for (int t = 0; t < HD; ++t) acc += W2[t] * U1b[(size_t)t * HD + jj];
        int ct = jj >> 4;
        int ks = 4 + (i >> 5);
        int lane = (((i & 31) >> 3) << 4) | (jj & 15);
        int j = i & 7;
        int g = (l << 12) | (ct << 9) | (ks << 6) | lane;
        fG1[(size_t)g * 8 + j] = f2bf(acc);
    } else if (idx < 66048) {
        int r = idx - 65536;
        int l = r >> 7, jj = r & 127;
        const float* U1b = upd_w1 + (size_t)l * 2 * HD * HD + (size_t)HD * HD;
        const float* b2 = msg_b2 + l * HD;
        float acc = 0.f;
        for (int t = 0; t < HD; ++t) acc += b2[t] * U1b[(size_t)t * HD + jj];
        c2[r] = acc;
    } else if (idx < 76048) {
        // dead
    } else if (idx < 84240) {
        int gl = idx - 76048;
        int l = gl >> 11, rem = gl & 2047;
        int ct = rem >> 8, ks = (rem >> 6) & 3, lane = rem & 63;
        int n = ct * 16 + (lane & 15), kb = ks * 32 + ((lane >> 4) << 3);
        int g = (l << 12) | (ct << 9) | (ks << 6) | lane;
        u16* dst = fG1 + (size_t)g * 8;
        const float* U = upd_w1 + (size_t)l * 256 * 128;
#pragma unroll
        for (int j = 0; j < 8; ++j) dst[j] = f2bf(U[(size_t)(kb + j) * 128 + n]);
    } else if (idx < 92432) {
        int gg = idx - 84240;
        int l = gg >> 11, r = gg & 2047;
        int ct = r >> 8, ks = (r >> 6) & 3, lane = r & 63;
        int n = ct * 16 + (lane & 15), kb = ks * 32 + ((lane >> 4) << 3);
        u16* dst = fG2 + (size_t)gg * 8;
        const float* W = upd_w2 + (size_t)l * 128 * 128;
#pragma unroll
        for (int j = 0; j < 8; ++j) dst[j] = f2bf(W[(size_t)(kb + j) * 128 + n]);
    } else if (idx < 108816) {
        int gg = idx - 92432;
        int li = gg >> 12, r = gg & 4095;
        int ct = r >> 8, ks = (r >> 6) & 3, lane = r & 63;
        int n = ct * 16 + (lane & 15), kb = ks * 32 + ((lane >> 4) << 3);
        u16* dst = fPQ + (size_t)gg * 8;
        const float* W = msg_w1 + (size_t)li * (2 * HD + EDIM) * HD;
#pragma unroll
        for (int j = 0; j < 8; ++j) {
            int k = kb + j;
            float v = (n < 128) ? W[(size_t)k * 128 + n] : W[(size_t)(128 + k) * 128 + (n - 128)];
            dst[j] = f2bf(v);
        }
    } else if (idx < 110864) {
        int r = idx - 108816;
        int ct = r >> 8, ks = (r >> 6) & 3, lane = r & 63;
        int n = ct * 16 + (lane & 15), kb = ks * 32 + ((lane >> 4) << 3);
        u16* dst = fDec + (size_t)r * 8;
#pragma unroll
        for (int j = 0; j < 8; ++j) dst[j] = f2bf(dec_w1[(size_t)(kb + j) * 128 + n]);
    } else if (idx < 112912) {
        int r = idx - 110864;
        int ct = r >> 8, ks = (r >> 6) & 3, lane = r & 63;
        int n = ct * 16 + (lane & 15), kb = ks * 32 + ((lane >> 4) << 3);
        u16* dst = fEnc + (size_t)r * 8;
#pragma unroll
        for (int j = 0; j < 8; ++j) dst[j] = f2bf(enc_w2[(size_t)(kb + j) * 128 + n]);
    }
}

// ---- k_enc: encoder (16 nodes per block) + PQ0 precompute ----

__global__ __launch_bounds__(512) void k_enc(
    const float* __restrict__ x, const float* __restrict__ ew1, const float* __restrict__ eb1,
    const u16* __restrict__ fEnc, const float* __restrict__ eb2, const u16* __restrict__ fPQ0,
    const float* __restrict__ mb1, u16* __restrict__ h_hi, u16* __restrict__ h_lo,
    float* __restrict__ PQf, u16* __restrict__ Qb) {
    __shared__ u16 tHi[2048], tLo[2048];
    int tid = threadIdx.x, w = tid >> 6, lane = tid & 63, q = lane >> 4, c = lane & 15;
    int band = blockIdx.x * 16;
    {
        int col = w * 16 + c;
        float wv[NIN];
#pragma unroll
        for (int k = 0; k < NIN; ++k) wv[k] = ew1[k * HD + col];
        float ebv = eb1[col];
#pragma unroll
        for (int reg = 0; reg < 4; ++reg) {
            int row = band + q * 4 + reg;
            float t = ebv;
#pragma unroll
            for (int k = 0; k < NIN; ++k) t += x[(size_t)row * NIN + k] * wv[k];
            t = fmaxf(t, 0.f);
            u16 hi, lo;
            split2(t, hi, lo);
            int r16 = q * 4 + reg;
            int a = r16 * 128 + (((col >> 3) ^ r16) << 3) + (col & 7);
            tHi[a] = hi;
            tLo[a] = lo;
        }
    }
    __syncthreads();
    short8 aH[4], aL[4];
#pragma unroll
    for (int ks = 0; ks < 4; ++ks) {
        int a = c * 128 + (((ks * 4 + q) ^ c) << 3);
        aH[ks] = *(const short8*)&tHi[a];
        aL[ks] = *(const short8*)&tLo[a];
    }
    f32x4 acc = {0, 0, 0, 0};
    {
        const u16* fb = fEnc + (size_t)w * 4 * 512 + lane * 8;
#pragma unroll
        for (int ks = 0; ks < 4; ++ks) {
            short8 b = *(const short8*)(fb + ks * 512);
            acc = MFMA(aH[ks], b, acc);
            acc = MFMA(aL[ks], b, acc);
        }
    }
    __syncthreads();
    {
        int col = w * 16 + c;
        float ebv = eb2[col];
#pragma unroll
        for (int reg = 0; reg < 4; ++reg) {
            int r16 = q * 4 + reg, row = band + r16;
            float hval = acc[reg] + ebv;
            u16 hi, lo;
            split2(hval, hi, lo);
            h_hi[(size_t)row * HD + col] = hi;
            h_lo[(size_t)row * HD + col] = lo;
            int a = r16 * 128 + (((col >> 3) ^ r16) << 3) + (col & 7);
            tHi[a] = hi;
            tLo[a] = lo;
        }
    }
    __syncthreads();
#pragma unroll
    for (int ks = 0; ks < 4; ++ks) {
        int a = c * 128 + (((ks * 4 + q) ^ c) << 3);
        aH[ks] = *(const short8*)&tHi[a];
        aL[ks] = *(const short8*)&tLo[a];
    }
#pragma unroll
    for (int i = 0; i < 2; ++i) {
        int ctg = w * 2 + i;
        const u16* fb = fPQ0 + (size_t)ctg * 4 * 512 + lane * 8;
        f32x4 a3 = {0, 0, 0, 0};
#pragma unroll
        for (int ks = 0; ks < 4; ++ks) {
            short8 b = *(const short8*)(fb + ks * 512);
            a3 = MFMA(aH[ks], b, a3);
            a3 = MFMA(aL[ks], b, a3);
        }
        int col = ctg * 16 + c;
        if (ctg < 8) {
            float bias = mb1[col];
#pragma unroll
            for (int reg = 0; reg < 4; ++reg)
                PQf[(size_t)(band + q * 4 + reg) * HD + col] = a3[reg] + bias;
        } else {
            int colq = col - 128;
#pragma unroll
            for (int reg = 0; reg < 4; ++reg)
                Qb[(size_t)(band + q * 4 + reg) * HD + colq] = f2bf(a3[reg]);
        }
    }
}

// ---- k_gath: edge aggregation, ONE WAVE PER NODE (4 nodes/block, no LDS,
// no barrier). Full batches of 16 edges (no predication: exact unrolled loops,
// all 16 bucket loads then all 16 row-gathers in flight), then one clamped
// tail batch (valid-slot clamp + cndmask discard -> no exec-mask churn, no OOB).
// Wave writes its bf16 hi/lo aggregate row directly.

__global__ __launch_bounds__(256) void k_gath(
    const float* __restrict__ PQf_in, const u16* __restrict__ Qb_in,
    const int* __restrict__ cnt, const float4* __restrict__ sea,
    const float* __restrict__ wc, u16* __restrict__ agg_hi, u16* __restrict__ agg_lo) {
    int w = threadIdx.x >> 6, lane = threadIdx.x & 63;
    int n = __builtin_amdgcn_readfirstlane(blockIdx.x * 4 + w);
    int cn = cnt[n];
    int cle = __builtin_amdgcn_readfirstlane(cn < CAP ? cn : CAP);
    int j = lane * 2;
    float2 p = *(const float2*)(PQf_in + (size_t)n * HD + j);
    float2 wcr0 = *(const float2*)(wc + j);
    float2 wcr1 = *(const float2*)(wc + HD + j);
    float2 wcr2 = *(const float2*)(wc + 2 * HD + j);
    const float4* bk = sea + (size_t)n * CAP;
    float acc0 = 0.f, acc1 = 0.f;
    int e = 0;
    for (; e + 16 <= cle; e += 16) {
        float4 A[16];
#pragma unroll
        for (int k = 0; k < 16; ++k) A[k] = bk[e + k];
        unsigned U[16];
#pragma unroll
        for (int k = 0; k < 16; ++k)
            U[k] = *(const unsigned*)(Qb_in + (size_t)__float_as_uint(A[k].w) * HD + j);
#pragma unroll
        for (int k = 0; k < 16; ++k) {
            float c0 = A[k].x * wcr0.x + A[k].y * wcr1.x + A[k].z * wcr2.x;
            float c1 = A[k].x * wcr0.y + A[k].y * wcr1.y + A[k].z * wcr2.y;
            acc0 += fmaxf(p.x + __uint_as_float(U[k] << 16) + c0, 0.f);
            acc1 += fmaxf(p.y + __uint_as_float(U[k] & 0xffff0000u) + c1, 0.f);
        }
    }
    int rem = cle - e;
    if (rem) {
        float4 A[16];
        unsigned U[16];
#pragma unroll
        for (int k = 0; k < 16; ++k) {
            int idx = e + (k < rem ? k : 0);  // clamp to a valid slot (e < cle here)
            A[k] = bk[idx];
        }
#pragma unroll
        for (int k = 0; k < 16; ++k)
            U[k] = *(const unsigned*)(Qb_in + (size_t)__float_as_uint(A[k].w) * HD + j);
#pragma unroll
        for (int k = 0; k < 16; ++k) {
            float c0 = A[k].x * wcr0.x + A[k].y * wcr1.x + A[k].z * wcr2.x;
            float c1 = A[k].x * wcr0.y + A[k].y * wcr1.y + A[k].z * wcr2.y;
            float t0 = fmaxf(p.x + __uint_as_float(U[k] << 16) + c0, 0.f);
            float t1 = fmaxf(p.y + __uint_as_float(U[k] & 0xffff0000u) + c1, 0.f);
            acc0 += (k < rem) ? t0 : 0.f;
            acc1 += (k < rem) ? t1 : 0.f;
        }
    }
    float invn = 1.0f / fmaxf((float)cn, 1.0f);
    float v0 = acc0 * invn, v1 = acc1 * invn;
    u16 h0, l0, h1, l1;
    split2(v0, h0, l0);
    split2(v1, h1, l1);
    *(ushort2*)(agg_hi + (size_t)n * HD + j) = make_ushort2(h0, h1);
    *(ushort2*)(agg_lo + (size_t)n * HD + j) = make_ushort2(l0, l1);
}

// ------- fused layer (512 thr / 8 waves): G1 -> G2 -> LN -> (PQ next | dec) -----
// A-fragments for G1: rows k<128 from h_hi/h_lo, k>=128 from agg_hi/agg_lo (global).

template <bool LAST>
__global__ __launch_bounds__(512) void k_layer(
    const u16* __restrict__ agg_hi, const u16* __restrict__ agg_lo, const int* __restrict__ cnt,
    u16* __restrict__ h_hi, u16* __restrict__ h_lo,
    const u16* __restrict__ fG1, const u16* __restrict__ fG2,
    const float* __restrict__ ub1, const float* __restrict__ c2l, const float* __restrict__ ub2,
    const float* __restrict__ g, const float* __restrict__ bb,
    const u16* __restrict__ fPQ, const float* __restrict__ nb1,
    float* __restrict__ PQf_out, u16* __restrict__ Qb_out,
    const u16* __restrict__ fDec, const float* __restrict__ db1, const float* __restrict__ dw2,
    const float* __restrict__ db2, float* __restrict__ out) {
    __shared__ u16 tHi[2048], tLo[2048];
    __shared__ float red[16][8][2];
    int tid = threadIdx.x, w = tid >> 6, lane = tid & 63, q = lane >> 4, c = lane & 15;
    int band = blockIdx.x * 16;
    // ======== G1: A = [h | agg] straight from global, 1 ctg per wave ========
    short8 aH[8], aL[8];
    {
        size_t rb = (size_t)(band + c) * HD + q * 8;
#pragma unroll
        for (int ks = 0; ks < 4; ++ks) {
            aH[ks] = *(const short8*)(h_hi + rb + ks * 32);
            aL[ks] = *(const short8*)(h_lo + rb + ks * 32);
            aH[4 + ks] = *(const short8*)(agg_hi + rb + ks * 32);
            aL[4 + ks] = *(const short8*)(agg_lo + rb + ks * 32);
        }
    }
    f32x4 acc = {0, 0, 0, 0};
    {
        const u16* fb = fG1 + (size_t)w * 8 * 512 + lane * 8;
#pragma unroll
        for (int ks = 0; ks < 8; ++ks) {
            short8 b = *(const short8*)(fb + ks * 512);
            acc = MFMA(aH[ks], b, acc);
            acc = MFMA(aL[ks], b, acc);
        }
    }
    float alv[4];
#pragma unroll
    for (int reg = 0; reg < 4; ++reg) alv[reg] = (cnt[band + q * 4 + reg] > 0) ? 1.f : 0.f;
    {
        int col = w * 16 + c;
        float u1b = ub1[col], cc = c2l[col];
#pragma unroll
        for (int reg = 0; reg < 4; ++reg) {
            int r16 = q * 4 + reg;
            float t = fmaxf(acc[reg] + u1b + alv[reg] * cc, 0.f);
            u16 hi, lo;
            split2(t, hi, lo);
            int a = r16 * 128 + (((col >> 3) ^ r16) << 3) + (col & 7);
            tHi[a] = hi;
            tLo[a] = lo;
        }
    }
    __syncthreads();
    // ======== G2: 1 ctg per wave ========
    short8 aH2[4], aL2[4];
#pragma unroll
    for (int ks = 0; ks < 4; ++ks) {
        int a = c * 128 + (((ks * 4 + q) ^ c) << 3);
        aH2[ks] = *(const short8*)&tHi[a];
        aL2[ks] = *(const short8*)&tLo[a];
    }
    f32x4 acc2 = {0, 0, 0, 0};
    {
        const u16* fb = fG2 + (size_t)w * 4 * 512 + lane * 8;
#pragma unroll
        for (int ks = 0; ks < 4; ++ks) {
            short8 b = *(const short8*)(fb + ks * 512);
            acc2 = MFMA(aH2[ks], b, acc2);
            acc2 = MFMA(aL2[ks], b, acc2);
        }
    }
    // ======== residual + LN ========
    float vv[4];
    {
        int col = w * 16 + c;
        float u2b = ub2[col];
#pragma unroll
        for (int reg = 0; reg < 4; ++reg) {
            size_t idx = (size_t)(band + q * 4 + reg) * HD + col;
            float hres = bf2f(h_hi[idx]) + bf2f(h_lo[idx]);
            vv[reg] = acc2[reg] + u2b + hres;
        }
    }
#pragma unroll
    for (int reg = 0; reg < 4; ++reg) {
        float s = vv[reg];
        float s2 = vv[reg] * vv[reg];
        for (int m = 1; m < 16; m <<= 1) {
            s += __shfl_xor(s, m);
            s2 += __shfl_xor(s2, m);
        }
        if (c == 0) {
            red[q * 4 + reg][w][0] = s;
            red[q * 4 + reg][w][1] = s2;
        }
    }
    __syncthreads();
    float mu[4], rs[4];
#pragma unroll
    for (int reg = 0; reg < 4; ++reg) {
        int r16 = q * 4 + reg;
        float S1 = 0.f, S2 = 0.f;
#pragma unroll
        for (int ww = 0; ww < 8; ++ww) {
            S1 += red[r16][ww][0];
            S2 += red[r16][ww][1];
        }
        float m = S1 * (1.f / HD);
        float var = S2 * (1.f / HD) - m * m;
        mu[reg] = m;
        rs[reg] = rsqrtf(var + LN_EPS);
    }
    {
        int col = w * 16 + c;
        float gg = g[col], bv = bb[col];
#pragma unroll
        for (int reg = 0; reg < 4; ++reg) {
            int r16 = q * 4 + reg;
            float o = (vv[reg] - mu[reg]) * rs[reg] * gg + bv;
            u16 hi, lo;
            split2(o, hi, lo);
            int a = r16 * 128 + (((col >> 3) ^ r16) << 3) + (col & 7);
            tHi[a] = hi;
            tLo[a] = lo;
            if (!LAST) {
                size_t idx = (size_t)(band + r16) * HD + col;
                h_hi[idx] = hi;
                h_lo[idx] = lo;
            }
        }
    }
    __syncthreads();
    short8 aH3[4], aL3[4];
#pragma unroll
    for (int ks = 0; ks < 4; ++ks) {
        int a = c * 128 + (((ks * 4 + q) ^ c) << 3);
        aH3[ks] = *(const short8*)&tHi[a];
        aL3[ks] = *(const short8*)&tLo[a];
    }
    if (!LAST) {
#pragma unroll
        for (int i = 0; i < 2; ++i) {
            int ctg = w * 2 + i;
            const u16* fb = fPQ + (size_t)ctg * 4 * 512 + lane * 8;
            f32x4 a3 = {0, 0, 0, 0};
#pragma unroll
            for (int ks = 0; ks < 4; ++ks) {
                short8 b = *(const short8*)(fb + ks * 512);
                a3 = MFMA(aH3[ks], b, a3);
                a3 = MFMA(aL3[ks], b, a3);
            }
            int col = ctg * 16 + c;
            if (ctg < 8) {
                float bias = nb1[col];
#pragma unroll
                for (int reg = 0; reg < 4; ++reg)
                    PQf_out[(size_t)(band + q * 4 + reg) * HD + col] = a3[reg] + bias;
            } else {
                int colq = col - 128;
#pragma unroll
                for (int reg = 0; reg < 4; ++reg)
                    Qb_out[(size_t)(band + q * 4 + reg) * HD + colq] = f2bf(a3[reg]);
            }
        }
    } else {
        float part[4];
        {
            const u16* fb = fDec + (size_t)w * 4 * 512 + lane * 8;
            f32x4 a3 = {0, 0, 0, 0};
#pragma unroll
            for (int ks = 0; ks < 4; ++ks) {
                short8 b = *(const short8*)(fb + ks * 512);
                a3 = MFMA(aH3[ks], b, a3);
                a3 = MFMA(aL3[ks], b, a3);
            }
            int col = w * 16 + c;
            float w2v = dw2[col], b1v = db1[col];
#pragma unroll
            for (int reg = 0; reg < 4; ++reg) part[reg] = fmaxf(a3[reg] + b1v, 0.f) * w2v;
        }
#pragma unroll
        for (int reg = 0; reg < 4; ++reg) {
            float s = part[reg];
            for (int m = 1; m < 16; m <<= 1) s += __shfl_xor(s, m);
            if (c == 0) red[q * 4 + reg][w][0] = s;
        }
        __syncthreads();
        if (tid < 16) {
            float s = db2[0];
#pragma unroll
            for (int ww = 0; ww < 8; ++ww) s += red[tid][ww][0];
            out[band + tid] = s;
        }
    }
}

// ---------------- launch ----------------

extern "C" void kernel_launch(void* const* d_in, const int* in_sizes, int n_in,
                              void* d_out, int out_size, void* d_ws, size_t ws_size,
                              hipStream_t stream) {
    const float* x = (const float*)d_in[0];
    const int* eidx = (const int*)d_in[1];
    const float* eattr = (const float*)d_in[2];
    const float* enc_w1 = (const float*)d_in[3];
    const float* enc_b1 = (const float*)d_in[4];
    const float* enc_w2 = (const float*)d_in[5];
    const float* enc_b2 = (const float*)d_in[6];
    const float* msg_w1 = (const float*)d_in[7];
    const float* msg_b1 = (const float*)d_in[8];
    const float* msg_w2 = (const float*)d_in[9];
    const float* msg_b2 = (const float*)d_in[10];
    const float* upd_w1 = (const float*)d_in[11];
    const float* upd_b1 = (const float*)d_in[12];
    const float* upd_w2 = (const float*)d_in[13];
    const float* upd_b2 = (const float*)d_in[14];
    const float* ln_g = (const float*)d_in[15];
    const float* ln_b = (const float*)d_in[16];
    const float* dec_w1 = (const float*)d_in[17];
    const float* dec_b1 = (const float*)d_in[18];
    const float* dec_w2 = (const float*)d_in[19];
    const float* dec_b2 = (const float*)d_in[20];
    const int* srcp = eidx;
    const int* tgtp = eidx + NE;

    char* base = (char*)d_ws;
    size_t off = 0;
    auto alloc = [&](size_t bytes) -> void* {
        off = (off + 15) & ~(size_t)15;
        void* p = base + off;
        off += bytes;
        return p;
    };
    float4* sea = (float4*)alloc((size_t)NN * CAP * 16);
    float* PQf0 = (float*)alloc((size_t)NN * HD * 4);
    float* PQf1 = (float*)alloc((size_t)NN * HD * 4);
    u16* Qb0 = (u16*)alloc((size_t)NN * HD * 2);
    u16* Qb1 = (u16*)alloc((size_t)NN * HD * 2);
    u16* h_hi = (u16*)alloc((size_t)NN * HD * 2);
    u16* h_lo = (u16*)alloc((size_t)NN * HD * 2);
    u16* agg_hi = (u16*)alloc((size_t)NN * HD * 2);
    u16* agg_lo = (u16*)alloc((size_t)NN * HD * 2);
    int* cnt = (int*)alloc((size_t)NN * 4);
    float* c2 = (float*)alloc((size_t)NL * HD * 4);
    u16* fG1 = (u16*)alloc((size_t)131072 * 2);
    u16* fG2 = (u16*)alloc((size_t)65536 * 2);
    u16* fPQ = (u16*)alloc((size_t)131072 * 2);
    u16* fDec = (u16*)alloc((size_t)16384 * 2);
    u16* fEnc = (u16*)alloc((size_t)16384 * 2);

    hipMemsetAsync(cnt, 0, (size_t)NN * 4, stream);
    k_prepscat<<<442 + (NE + 255) / 256, 256, 0, stream>>>(
        msg_w2, msg_b2, upd_w1, upd_w2, msg_w1, dec_w1, enc_w2,
        c2, fG1, fG2, fPQ, fDec, fEnc,
        srcp, tgtp, eattr, cnt, sea);
    k_enc<<<625, 512, 0, stream>>>(x, enc_w1, enc_b1, fEnc, enc_b2, fPQ,
                                   msg_b1, h_hi, h_lo, PQf0, Qb0);

    float* PQin = PQf0;
    u16* Qin = Qb0;
    float* PQout = PQf1;
    u16* Qout = Qb1;
    for (int l = 0; l < NL; ++l) {
        const float* wc = msg_w1 + (size_t)l * (2 * HD + EDIM) * HD + (size_t)2 * HD * HD;
        k_gath<<<NN / 4, 256, 0, stream>>>(PQin, Qin, cnt, sea, wc, agg_hi, agg_lo);
        if (l < NL - 1) {
            k_layer<false><<<NN / 16, 512, 0, stream>>>(
                agg_hi, agg_lo, cnt, h_hi, h_lo,
                fG1 + (size_t)l * 32768, fG2 + (size_t)l * 16384,
                upd_b1 + l * HD, c2 + l * HD, upd_b2 + l * HD, ln_g + l * HD, ln_b + l * HD,
                fPQ + (size_t)(l + 1) * 32768, msg_b1 + (size_t)(l + 1) * HD, PQout, Qout,
                nullptr, nullptr, nullptr, nullptr, nullptr);
        } else {
            k_layer<true><<<NN / 16, 512, 0, stream>>>(
                agg_hi, agg_lo, cnt, h_hi, h_lo,
                fG1 + (size_t)l * 32768, fG2 + (size_t)l * 16384,
                upd_b1 + l * HD, c2 + l * HD, upd_b2 + l * HD, ln_g + l * HD, ln_b + l * HD,
                nullptr, nullptr, nullptr, nullptr,
                fDec, dec_b1, dec_w2, dec_b2, (float*)d_out);
        }
        float* tf = PQin; PQin = PQout; PQout = tf;
        u16* tq = Qin; Qin = Qout; Qout = tq;
    }
}

// Round 6
// 302.488 us; speedup vs baseline: 1.6841x; 1.0178x over previous
//
#include <hip/hip_runtime.h>

#define NN 10000
#define NE 400000
#define HD 128
#define NIN 6
#define EDIM 3
#define NL 4
#define CAP 96
#define LN_EPS 1e-5f

typedef unsigned short u16;
using short8 = __attribute__((ext_vector_type(8))) short;
using f32x4 = __attribute__((ext_vector_type(4))) float;

__device__ __forceinline__ u16 f2bf(float x) {
    unsigned u = __float_as_uint(x);
    return (u16)((u + 0x7fff + ((u >> 16) & 1)) >> 16);
}
__device__ __forceinline__ float bf2f(u16 h) { return __uint_as_float(((unsigned)h) << 16); }
__device__ __forceinline__ void split2(float x, u16& hi, u16& lo) {
    hi = f2bf(x);
    lo = f2bf(x - bf2f(hi));
}
#define MFMA(a, b, c) __builtin_amdgcn_mfma_f32_16x16x32_bf16((a), (b), (c), 0, 0, 0)

// ---- k_prepscat: weight prep (blocks [0,442)) + edge scatter (blocks [442,...)).
// cnt zeroed by hipMemsetAsync before this kernel.

__global__ __launch_bounds__(256) void k_prepscat(
    const float* __restrict__ msg_w2, const float* __restrict__ msg_b2, const float* __restrict__ upd_w1,
    const float* __restrict__ upd_w2, const float* __restrict__ msg_w1, const float* __restrict__ dec_w1,
    const float* __restrict__ enc_w2, float* __restrict__ c2,
    u16* __restrict__ fG1, u16* __restrict__ fG2, u16* __restrict__ fPQ,
    u16* __restrict__ fDec, u16* __restrict__ fEnc,
    const int* __restrict__ srcp, const int* __restrict__ tgtp, const float* __restrict__ eattr,
    int* __restrict__ cnt, float4* __restrict__ sea) {
    if (blockIdx.x >= 442) {
        int e = (blockIdx.x - 442) * 256 + threadIdx.x;
        if (e < NE) {
            int t = tgtp[e];
            int pos = atomicAdd(&cnt[t], 1);
            if (pos < CAP) {
                sea[t * CAP + pos] = make_float4(eattr[e * 3], eattr[e * 3 + 1], eattr[e * 3 + 2],
                                                 __uint_as_float((unsigned)srcp[e]));
            }
        }
        return;
    }
    int idx = blockIdx.x * 256 + threadIdx.x;
    if (idx < 65536) {
        int l = idx >> 14, rem = idx & 16383, i = rem >> 7, jj = rem & 127;
        const float* U1b = upd_w1 + (size_t)l * 2 * HD * HD + (size_t)HD * HD;
        const float* W2 = msg_w2 + (size_t)l * HD * HD + (size_t)i * HD;
        float acc = 0.f;
        for (int t = 0; t < HD; ++t) acc += W2[t] * U1b[(size_t)t * HD + jj];
        int ct = jj >> 4;
        int ks = 4 + (i >> 5);
        int lane = (((i & 31) >> 3) << 4) | (jj & 15);
        int j = i & 7;
        int g = (l << 12) | (ct << 9) | (ks << 6) | lane;
        fG1[(size_t)g * 8 + j] = f2bf(acc);
    } else if (idx < 66048) {
        int r = idx - 65536;
        int l = r >> 7, jj = r & 127;
        const float* U1b = upd_w1 + (size_t)l * 2 * HD * HD + (size_t)HD * HD;
        const float* b2 = msg_b2 + l * HD;
        float acc = 0.f;
        for (int t = 0; t < HD; ++t) acc += b2[t] * U1b[(size_t)t * HD + jj];
        c2[r] = acc;
    } else if (idx < 76048) {
        // dead
    } else if (idx < 84240) {
        int gl = idx - 76048;
        int l = gl >> 11, rem = gl & 2047;
        int ct = rem >> 8, ks = (rem >> 6) & 3, lane = rem & 63;
        int n = ct * 16 + (lane & 15), kb = ks * 32 + ((lane >> 4) << 3);
        int g = (l << 12) | (ct << 9) | (ks << 6) | lane;
        u16* dst = fG1 + (size_t)g * 8;
        const float* U = upd_w1 + (size_t)l * 256 * 128;
#pragma unroll
        for (int j = 0; j < 8; ++j) dst[j] = f2bf(U[(size_t)(kb + j) * 128 + n]);
    } else if (idx < 92432) {
        int gg = idx - 84240;
        int l = gg >> 11, r = gg & 2047;
        int ct = r >> 8, ks = (r >> 6) & 3, lane = r & 63;
        int n = ct * 16 + (lane & 15), kb = ks * 32 + ((lane >> 4) << 3);
        u16* dst = fG2 + (size_t)gg * 8;
        const float* W = upd_w2 + (size_t)l * 128 * 128;
#pragma unroll
        for (int j = 0; j < 8; ++j) dst[j] = f2bf(W[(size_t)(kb + j) * 128 + n]);
    } else if (idx < 108816) {
        int gg = idx - 92432;
        int li = gg >> 12, r = gg & 4095;
        int ct = r >> 8, ks = (r >> 6) & 3, lane = r & 63;
        int n = ct * 16 + (lane & 15), kb = ks * 32 + ((lane >> 4) << 3);
        u16* dst = fPQ + (size_t)gg * 8;
        const float* W = msg_w1 + (size_t)li * (2 * HD + EDIM) * HD;
#pragma unroll
        for (int j = 0; j < 8; ++j) {
            int k = kb + j;
            float v = (n < 128) ? W[(size_t)k * 128 + n] : W[(size_t)(128 + k) * 128 + (n - 128)];
            dst[j] = f2bf(v);
        }
    } else if (idx < 110864) {
        int r = idx - 108816;
        int ct = r >> 8, ks = (r >> 6) & 3, lane = r & 63;
        int n = ct * 16 + (lane & 15), kb = ks * 32 + ((lane >> 4) << 3);
        u16* dst = fDec + (size_t)r * 8;
#pragma unroll
        for (int j = 0; j < 8; ++j) dst[j] = f2bf(dec_w1[(size_t)(kb + j) * 128 + n]);
    } else if (idx < 112912) {
        int r = idx - 110864;
        int ct = r >> 8, ks = (r >> 6) & 3, lane = r & 63;
        int n = ct * 16 + (lane & 15), kb = ks * 32 + ((lane >> 4) << 3);
        u16* dst = fEnc + (size_t)r * 8;
#pragma unroll
        for (int j = 0; j < 8; ++j) dst[j] = f2bf(enc_w2[(size_t)(kb + j) * 128 + n]);
    }
}

// ---- k_enc: encoder (16 nodes per block) + PQ0 precompute ----

__global__ __launch_bounds__(512) void k_enc(
    const float* __restrict__ x, const float* __restrict__ ew1, const float* __restrict__ eb1,
    const u16* __restrict__ fEnc, const float* __restrict__ eb2, const u16* __restrict__ fPQ0,
    const float* __restrict__ mb1, u16* __restrict__ h_hi, u16* __restrict__ h_lo,
    float* __restrict__ PQf, u16* __restrict__ Qb) {
    __shared__ u16 tHi[2048], tLo[2048];
    int tid = threadIdx.x, w = tid >> 6, lane = tid & 63, q = lane >> 4, c = lane & 15;
    int band = blockIdx.x * 16;
    {
        int col = w * 16 + c;
        float wv[NIN];
#pragma unroll
        for (int k = 0; k < NIN; ++k) wv[k] = ew1[k * HD + col];
        float ebv = eb1[col];
#pragma unroll
        for (int reg = 0; reg < 4; ++reg) {
            int row = band + q * 4 + reg;
            float t = ebv;
#pragma unroll
            for (int k = 0; k < NIN; ++k) t += x[(size_t)row * NIN + k] * wv[k];
            t = fmaxf(t, 0.f);
            u16 hi, lo;
            split2(t, hi, lo);
            int r16 = q * 4 + reg;
            int a = r16 * 128 + (((col >> 3) ^ r16) << 3) + (col & 7);
            tHi[a] = hi;
            tLo[a] = lo;
        }
    }
    __syncthreads();
    short8 aH[4], aL[4];
#pragma unroll
    for (int ks = 0; ks < 4; ++ks) {
        int a = c * 128 + (((ks * 4 + q) ^ c) << 3);
        aH[ks] = *(const short8*)&tHi[a];
        aL[ks] = *(const short8*)&tLo[a];
    }
    f32x4 acc = {0, 0, 0, 0};
    {
        const u16* fb = fEnc + (size_t)w * 4 * 512 + lane * 8;
#pragma unroll
        for (int ks = 0; ks < 4; ++ks) {
            short8 b = *(const short8*)(fb + ks * 512);
            acc = MFMA(aH[ks], b, acc);
            acc = MFMA(aL[ks], b, acc);
        }
    }
    __syncthreads();
    {
        int col = w * 16 + c;
        float ebv = eb2[col];
#pragma unroll
        for (int reg = 0; reg < 4; ++reg) {
            int r16 = q * 4 + reg, row = band + r16;
            float hval = acc[reg] + ebv;
            u16 hi, lo;
            split2(hval, hi, lo);
            h_hi[(size_t)row * HD + col] = hi;
            h_lo[(size_t)row * HD + col] = lo;
            int a = r16 * 128 + (((col >> 3) ^ r16) << 3) + (col & 7);
            tHi[a] = hi;
            tLo[a] = lo;
        }
    }
    __syncthreads();
#pragma unroll
    for (int ks = 0; ks < 4; ++ks) {
        int a = c * 128 + (((ks * 4 + q) ^ c) << 3);
        aH[ks] = *(const short8*)&tHi[a];
        aL[ks] = *(const short8*)&tLo[a];
    }
#pragma unroll
    for (int i = 0; i < 2; ++i) {
        int ctg = w * 2 + i;
        const u16* fb = fPQ0 + (size_t)ctg * 4 * 512 + lane * 8;
        f32x4 a3 = {0, 0, 0, 0};
#pragma unroll
        for (int ks = 0; ks < 4; ++ks) {
            short8 b = *(const short8*)(fb + ks * 512);
            a3 = MFMA(aH[ks], b, a3);
            a3 = MFMA(aL[ks], b, a3);
        }
        int col = ctg * 16 + c;
        if (ctg < 8) {
            float bias = mb1[col];
#pragma unroll
            for (int reg = 0; reg < 4; ++reg)
                PQf[(size_t)(band + q * 4 + reg) * HD + col] = a3[reg] + bias;
        } else {
            int colq = col - 128;
#pragma unroll
            for (int reg = 0; reg < 4; ++reg)
                Qb[(size_t)(band + q * 4 + reg) * HD + colq] = f2bf(a3[reg]);
        }
    }
}

// ---- k_gath: edge aggregation, one wave per node. Two-stage software pipeline
// over uniform batches of 8: while batch b's gathers are consumed, batch b+1's
// bucket loads (scalar, SGPR) AND its Qb gathers (VGPR) are already in flight —
// 16 gathers + 8 s_loads outstanding continuously. Dual even/odd accumulators
// break the serial add chain. Clamped tail batch (cndmask discard, no OOB).

__global__ __launch_bounds__(256) void k_gath(
    const float* __restrict__ PQf_in, const u16* __restrict__ Qb_in,
    const int* __restrict__ cnt, const float4* __restrict__ sea,
    const float* __restrict__ wc, u16* __restrict__ agg_hi, u16* __restrict__ agg_lo) {
    int w = threadIdx.x >> 6, lane = threadIdx.x & 63;
    int n = __builtin_amdgcn_readfirstlane(blockIdx.x * 4 + w);
    int cn = cnt[n];
    int cle = __builtin_amdgcn_readfirstlane(cn < CAP ? cn : CAP);
    int j = lane * 2;
    float2 p = *(const float2*)(PQf_in + (size_t)n * HD + j);
    float2 wcr0 = *(const float2*)(wc + j);
    float2 wcr1 = *(const float2*)(wc + HD + j);
    float2 wcr2 = *(const float2*)(wc + 2 * HD + j);
    const float4* bk = sea + (size_t)n * CAP;
    float e0 = 0.f, e1 = 0.f, o0 = 0.f, o1 = 0.f;
    float4 A0[8], A1[8];
    unsigned U0[8], U1[8];

    auto LA = [&](float4* A, int b) {
#pragma unroll
        for (int k = 0; k < 8; ++k) A[k] = bk[b * 8 + k];
    };
    auto IU = [&](unsigned* U, const float4* A) {
#pragma unroll
        for (int k = 0; k < 8; ++k)
            U[k] = *(const unsigned*)(Qb_in + (size_t)__float_as_uint(A[k].w) * HD + j);
    };
    auto CO = [&](const float4* A, const unsigned* U) {
#pragma unroll
        for (int k = 0; k < 8; ++k) {
            float c0 = A[k].x * wcr0.x + A[k].y * wcr1.x + A[k].z * wcr2.x;
            float c1 = A[k].x * wcr0.y + A[k].y * wcr1.y + A[k].z * wcr2.y;
            float t0 = fmaxf(p.x + __uint_as_float(U[k] << 16) + c0, 0.f);
            float t1 = fmaxf(p.y + __uint_as_float(U[k] & 0xffff0000u) + c1, 0.f);
            if (k & 1) { o0 += t0; o1 += t1; } else { e0 += t0; e1 += t1; }
        }
    };

    int nb = cle >> 3;
    int b = 0;
    if (nb) {
        LA(A0, 0);
        IU(U0, A0);
        for (; b + 2 <= nb; b += 2) {
            LA(A1, b + 1);
            IU(U1, A1);           // batch b+1 gathers in flight over batch b's consume
            CO(A0, U0);
            if (b + 2 < nb) { LA(A0, b + 2); IU(U0, A0); }
            CO(A1, U1);
        }
        if (b < nb) { CO(A0, U0); ++b; }  // odd leftover (pre-issued)
    }
    int e = nb * 8;
    int rem = cle - e;
    if (rem) {
#pragma unroll
        for (int k = 0; k < 8; ++k) A0[k] = bk[e + (k < rem ? k : 0)];  // clamp (e < cle)
        IU(U0, A0);
#pragma unroll
        for (int k = 0; k < 8; ++k) {
            float c0 = A0[k].x * wcr0.x + A0[k].y * wcr1.x + A0[k].z * wcr2.x;
            float c1 = A0[k].x * wcr0.y + A0[k].y * wcr1.y + A0[k].z * wcr2.y;
            float t0 = fmaxf(p.x + __uint_as_float(U0[k] << 16) + c0, 0.f);
            float t1 = fmaxf(p.y + __uint_as_float(U0[k] & 0xffff0000u) + c1, 0.f);
            t0 = (k < rem) ? t0 : 0.f;
            t1 = (k < rem) ? t1 : 0.f;
            if (k & 1) { o0 += t0; o1 += t1; } else { e0 += t0; e1 += t1; }
        }
    }
    float invn = 1.0f / fmaxf((float)cn, 1.0f);
    float v0 = (e0 + o0) * invn, v1 = (e1 + o1) * invn;
    u16 h0, l0, h1, l1;
    split2(v0, h0, l0);
    split2(v1, h1, l1);
    *(ushort2*)(agg_hi + (size_t)n * HD + j) = make_ushort2(h0, h1);
    *(ushort2*)(agg_lo + (size_t)n * HD + j) = make_ushort2(l0, l1);
}

// ------- fused layer (512 thr / 8 waves): G1 -> G2 -> LN -> (PQ next | dec) -----
// A-fragments for G1: rows k<128 from h_hi/h_lo, k>=128 from agg_hi/agg_lo (global).
// All MFMA chains use dual accumulators (2x ILP on the matrix pipe).

template <bool LAST>
__global__ __launch_bounds__(512) void k_layer(
    const u16* __restrict__ agg_hi, const u16* __restrict__ agg_lo, const int* __restrict__ cnt,
    u16* __restrict__ h_hi, u16* __restrict__ h_lo,
    const u16* __restrict__ fG1, const u16* __restrict__ fG2,
    const float* __restrict__ ub1, const float* __restrict__ c2l, const float* __restrict__ ub2,
    const float* __restrict__ g, const float* __restrict__ bb,
    const u16* __restrict__ fPQ, const float* __restrict__ nb1,
    float* __restrict__ PQf_out, u16* __restrict__ Qb_out,
    const u16* __restrict__ fDec, const float* __restrict__ db1, const float* __restrict__ dw2,
    const float* __restrict__ db2, float* __restrict__ out) {
    __shared__ u16 tHi[2048], tLo[2048];
    __shared__ float red[16][8][2];
    int tid = threadIdx.x, w = tid >> 6, lane = tid & 63, q = lane >> 4, c = lane & 15;
    int band = blockIdx.x * 16;
    // ======== G1: A = [h | agg] straight from global, 1 ctg per wave ========
    short8 aH[8], aL[8];
    {
        size_t rb = (size_t)(band + c) * HD + q * 8;
#pragma unroll
        for (int ks = 0; ks < 4; ++ks) {
            aH[ks] = *(const short8*)(h_hi + rb + ks * 32);
            aL[ks] = *(const short8*)(h_lo + rb + ks * 32);
            aH[4 + ks] = *(const short8*)(agg_hi + rb + ks * 32);
            aL[4 + ks] = *(const short8*)(agg_lo + rb + ks * 32);
        }
    }
    f32x4 accA = {0, 0, 0, 0}, accB = {0, 0, 0, 0};
    {
        const u16* fb = fG1 + (size_t)w * 8 * 512 + lane * 8;
#pragma unroll
        for (int ks = 0; ks < 4; ++ks) {
            short8 bA = *(const short8*)(fb + ks * 512);
            short8 bB = *(const short8*)(fb + (ks + 4) * 512);
            accA = MFMA(aH[ks], bA, accA);
            accB = MFMA(aH[ks + 4], bB, accB);
            accA = MFMA(aL[ks], bA, accA);
            accB = MFMA(aL[ks + 4], bB, accB);
        }
    }
    f32x4 acc = accA + accB;
    float alv[4];
#pragma unroll
    for (int reg = 0; reg < 4; ++reg) alv[reg] = (cnt[band + q * 4 + reg] > 0) ? 1.f : 0.f;
    {
        int col = w * 16 + c;
        float u1b = ub1[col], cc = c2l[col];
#pragma unroll
        for (int reg = 0; reg < 4; ++reg) {
            int r16 = q * 4 + reg;
            float t = fmaxf(acc[reg] + u1b + alv[reg] * cc, 0.f);
            u16 hi, lo;
            split2(t, hi, lo);
            int a = r16 * 128 + (((col >> 3) ^ r16) << 3) + (col & 7);
            tHi[a] = hi;
            tLo[a] = lo;
        }
    }
    __syncthreads();
    // ======== G2: 1 ctg per wave ========
    short8 aH2[4], aL2[4];
#pragma unroll
    for (int ks = 0; ks < 4; ++ks) {
        int a = c * 128 + (((ks * 4 + q) ^ c) << 3);
        aH2[ks] = *(const short8*)&tHi[a];
        aL2[ks] = *(const short8*)&tLo[a];
    }
    f32x4 acc2A = {0, 0, 0, 0}, acc2B = {0, 0, 0, 0};
    {
        const u16* fb = fG2 + (size_t)w * 4 * 512 + lane * 8;
#pragma unroll
        for (int ks = 0; ks < 2; ++ks) {
            short8 bA = *(const short8*)(fb + ks * 512);
            short8 bB = *(const short8*)(fb + (ks + 2) * 512);
            acc2A = MFMA(aH2[ks], bA, acc2A);
            acc2B = MFMA(aH2[ks + 2], bB, acc2B);
            acc2A = MFMA(aL2[ks], bA, acc2A);
            acc2B = MFMA(aL2[ks + 2], bB, acc2B);
        }
    }
    f32x4 acc2 = acc2A + acc2B;
    // ======== residual + LN ========
    float vv[4];
    {
        int col = w * 16 + c;
        float u2b = ub2[col];
#pragma unroll
        for (int reg = 0; reg < 4; ++reg) {
            size_t idx = (size_t)(band + q * 4 + reg) * HD + col;
            float hres = bf2f(h_hi[idx]) + bf2f(h_lo[idx]);
            vv[reg] = acc2[reg] + u2b + hres;
        }
    }
#pragma unroll
    for (int reg = 0; reg < 4; ++reg) {
        float s = vv[reg];
        float s2 = vv[reg] * vv[reg];
        for (int m = 1; m < 16; m <<= 1) {
            s += __shfl_xor(s, m);
            s2 += __shfl_xor(s2, m);
        }
        if (c == 0) {
            red[q * 4 + reg][w][0] = s;
            red[q * 4 + reg][w][1] = s2;
        }
    }
    __syncthreads();
    float mu[4], rs[4];
#pragma unroll
    for (int reg = 0; reg < 4; ++reg) {
        int r16 = q * 4 + reg;
        float S1 = 0.f, S2 = 0.f;
#pragma unroll
        for (int ww = 0; ww < 8; ++ww) {
            S1 += red[r16][ww][0];
            S2 += red[r16][ww][1];
        }
        float m = S1 * (1.f / HD);
        float var = S2 * (1.f / HD) - m * m;
        mu[reg] = m;
        rs[reg] = rsqrtf(var + LN_EPS);
    }
    {
        int col = w * 16 + c;
        float gg = g[col], bv = bb[col];
#pragma unroll
        for (int reg = 0; reg < 4; ++reg) {
            int r16 = q * 4 + reg;
            float o = (vv[reg] - mu[reg]) * rs[reg] * gg + bv;
            u16 hi, lo;
            split2(o, hi, lo);
            int a = r16 * 128 + (((col >> 3) ^ r16) << 3) + (col & 7);
            tHi[a] = hi;
            tLo[a] = lo;
            if (!LAST) {
                size_t idx = (size_t)(band + r16) * HD + col;
                h_hi[idx] = hi;
                h_lo[idx] = lo;
            }
        }
    }
    __syncthreads();
    short8 aH3[4], aL3[4];
#pragma unroll
    for (int ks = 0; ks < 4; ++ks) {
        int a = c * 128 + (((ks * 4 + q) ^ c) << 3);
        aH3[ks] = *(const short8*)&tHi[a];
        aL3[ks] = *(const short8*)&tLo[a];
    }
    if (!LAST) {
#pragma unroll
        for (int i = 0; i < 2; ++i) {
            int ctg = w * 2 + i;
            const u16* fb = fPQ + (size_t)ctg * 4 * 512 + lane * 8;
            f32x4 a3A = {0, 0, 0, 0}, a3B = {0, 0, 0, 0};
#pragma unroll
            for (int ks = 0; ks < 2; ++ks) {
                short8 bA = *(const short8*)(fb + ks * 512);
                short8 bB = *(const short8*)(fb + (ks + 2) * 512);
                a3A = MFMA(aH3[ks], bA, a3A);
                a3B = MFMA(aH3[ks + 2], bB, a3B);
                a3A = MFMA(aL3[ks], bA, a3A);
                a3B = MFMA(aL3[ks + 2], bB, a3B);
            }
            f32x4 a3 = a3A + a3B;
            int col = ctg * 16 + c;
            if (ctg < 8) {
                float bias = nb1[col];
#pragma unroll
                for (int reg = 0; reg < 4; ++reg)
                    PQf_out[(size_t)(band + q * 4 + reg) * HD + col] = a3[reg] + bias;
            } else {
                int colq = col - 128;
#pragma unroll
                for (int reg = 0; reg < 4; ++reg)
                    Qb_out[(size_t)(band + q * 4 + reg) * HD + colq] = f2bf(a3[reg]);
            }
        }
    } else {
        float part[4];
        {
            const u16* fb = fDec + (size_t)w * 4 * 512 + lane * 8;
            f32x4 a3A = {0, 0, 0, 0}, a3B = {0, 0, 0, 0};
#pragma unroll
            for (int ks = 0; ks < 2; ++ks) {
                short8 bA = *(const short8*)(fb + ks * 512);
                short8 bB = *(const short8*)(fb + (ks + 2) * 512);
                a3A = MFMA(aH3[ks], bA, a3A);
                a3B = MFMA(aH3[ks + 2], bB, a3B);
                a3A = MFMA(aL3[ks], bA, a3A);
                a3B = MFMA(aL3[ks + 2], bB, a3B);
            }
            f32x4 a3 = a3A + a3B;
            int col = w * 16 + c;
            float w2v = dw2[col], b1v = db1[col];
#pragma unroll
            for (int reg = 0; reg < 4; ++reg) part[reg] = fmaxf(a3[reg] + b1v, 0.f) * w2v;
        }
#pragma unroll
        for (int reg = 0; reg < 4; ++reg) {
            float s = part[reg];
            for (int m = 1; m < 16; m <<= 1) s += __shfl_xor(s, m);
            if (c == 0) red[q * 4 + reg][w][0] = s;
        }
        __syncthreads();
        if (tid < 16) {
            float s = db2[0];
#pragma unroll
            for (int ww = 0; ww < 8; ++ww) s += red[tid][ww][0];
            out[band + tid] = s;
        }
    }
}

// ---------------- launch ----------------

extern "C" void kernel_launch(void* const* d_in, const int* in_sizes, int n_in,
                              void* d_out, int out_size, void* d_ws, size_t ws_size,
                              hipStream_t stream) {
    const float* x = (const float*)d_in[0];
    const int* eidx = (const int*)d_in[1];
    const float* eattr = (const float*)d_in[2];
    const float* enc_w1 = (const float*)d_in[3];
    const float* enc_b1 = (const float*)d_in[4];
    const float* enc_w2 = (const float*)d_in[5];
    const float* enc_b2 = (const float*)d_in[6];
    const float* msg_w1 = (const float*)d_in[7];
    const float* msg_b1 = (const float*)d_in[8];
    const float* msg_w2 = (const float*)d_in[9];
    const float* msg_b2 = (const float*)d_in[10];
    const float* upd_w1 = (const float*)d_in[11];
    const float* upd_b1 = (const float*)d_in[12];
    const float* upd_w2 = (const float*)d_in[13];
    const float* upd_b2 = (const float*)d_in[14];
    const float* ln_g = (const float*)d_in[15];
    const float* ln_b = (const float*)d_in[16];
    const float* dec_w1 = (const float*)d_in[17];
    const float* dec_b1 = (const float*)d_in[18];
    const float* dec_w2 = (const float*)d_in[19];
    const float* dec_b2 = (const float*)d_in[20];
    const int* srcp = eidx;
    const int* tgtp = eidx + NE;

    char* base = (char*)d_ws;
    size_t off = 0;
    auto alloc = [&](size_t bytes) -> void* {
        off = (off + 15) & ~(size_t)15;
        void* p = base + off;
        off += bytes;
        return p;
    };
    float4* sea = (float4*)alloc((size_t)NN * CAP * 16);
    float* PQf0 = (float*)alloc((size_t)NN * HD * 4);
    float* PQf1 = (float*)alloc((size_t)NN * HD * 4);
    u16* Qb0 = (u16*)alloc((size_t)NN * HD * 2);
    u16* Qb1 = (u16*)alloc((size_t)NN * HD * 2);
    u16* h_hi = (u16*)alloc((size_t)NN * HD * 2);
    u16* h_lo = (u16*)alloc((size_t)NN * HD * 2);
    u16* agg_hi = (u16*)alloc((size_t)NN * HD * 2);
    u16* agg_lo = (u16*)alloc((size_t)NN * HD * 2);
    int* cnt = (int*)alloc((size_t)NN * 4);
    float* c2 = (float*)alloc((size_t)NL * HD * 4);
    u16* fG1 = (u16*)alloc((size_t)131072 * 2);
    u16* fG2 = (u16*)alloc((size_t)65536 * 2);
    u16* fPQ = (u16*)alloc((size_t)131072 * 2);
    u16* fDec = (u16*)alloc((size_t)16384 * 2);
    u16* fEnc = (u16*)alloc((size_t)16384 * 2);

    hipMemsetAsync(cnt, 0, (size_t)NN * 4, stream);
    k_prepscat<<<442 + (NE + 255) / 256, 256, 0, stream>>>(
        msg_w2, msg_b2, upd_w1, upd_w2, msg_w1, dec_w1, enc_w2,
        c2, fG1, fG2, fPQ, fDec, fEnc,
        srcp, tgtp, eattr, cnt, sea);
    k_enc<<<625, 512, 0, stream>>>(x, enc_w1, enc_b1, fEnc, enc_b2, fPQ,
                                   msg_b1, h_hi, h_lo, PQf0, Qb0);

    float* PQin = PQf0;
    u16* Qin = Qb0;
    float* PQout = PQf1;
    u16* Qout = Qb1;
    for (int l = 0; l < NL; ++l) {
        const float* wc = msg_w1 + (size_t)l * (2 * HD + EDIM) * HD + (size_t)2 * HD * HD;
        k_gath<<<NN / 4, 256, 0, stream>>>(PQin, Qin, cnt, sea, wc, agg_hi, agg_lo);
        if (l < NL - 1) {
            k_layer<false><<<NN / 16, 512, 0, stream>>>(
                agg_hi, agg_lo, cnt, h_hi, h_lo,
                fG1 + (size_t)l * 32768, fG2 + (size_t)l * 16384,
                upd_b1 + l * HD, c2 + l * HD, upd_b2 + l * HD, ln_g + l * HD, ln_b + l * HD,
                fPQ + (size_t)(l + 1) * 32768, msg_b1 + (size_t)(l + 1) * HD, PQout, Qout,
                nullptr, nullptr, nullptr, nullptr, nullptr);
        } else {
            k_layer<true><<<NN / 16, 512, 0, stream>>>(
                agg_hi, agg_lo, cnt, h_hi, h_lo,
                fG1 + (size_t)l * 32768, fG2 + (size_t)l * 16384,
                upd_b1 + l * HD, c2 + l * HD, upd_b2 + l * HD, ln_g + l * HD, ln_b + l * HD,
                nullptr, nullptr, nullptr, nullptr,
                fDec, dec_b1, dec_w2, dec_b2, (float*)d_out);
        }
        float* tf = PQin; PQin = PQout; PQout = tf;
        u16* tq = Qin; Qin = Qout; Qout = tq;
    }
}

// Round 7
// 286.652 us; speedup vs baseline: 1.7771x; 1.0552x over previous
//
#include <hip/hip_runtime.h>

#define NN 10000
#define NE 400000
#define HD 128
#define NIN 6
#define EDIM 3
#define NL 4
#define CAP 96
#define LN_EPS 1e-5f

typedef unsigned short u16;
using short8 = __attribute__((ext_vector_type(8))) short;
using f32x4 = __attribute__((ext_vector_type(4))) float;

__device__ __forceinline__ u16 f2bf(float x) {
    unsigned u = __float_as_uint(x);
    return (u16)((u + 0x7fff + ((u >> 16) & 1)) >> 16);
}
__device__ __forceinline__ float bf2f(u16 h) { return __uint_as_float(((unsigned)h) << 16); }
__device__ __forceinline__ void split2(float x, u16& hi, u16& lo) {
    hi = f2bf(x);
    lo = f2bf(x - bf2f(hi));
}
#define MFMA(a, b, c) __builtin_amdgcn_mfma_f32_16x16x32_bf16((a), (b), (c), 0, 0, 0)

// ---- k_prepscat: weight prep (blocks [0,442)) + edge scatter (blocks [442,...)).
// cnt zeroed by hipMemsetAsync before this kernel.

__global__ __launch_bounds__(256) void k_prepscat(
    const float* __restrict__ msg_w2, const float* __restrict__ msg_b2, const float* __restrict__ upd_w1,
    const float* __restrict__ upd_w2, const float* __restrict__ msg_w1, const float* __restrict__ dec_w1,
    const float* __restrict__ enc_w2, float* __restrict__ c2,
    u16* __restrict__ fG1, u16* __restrict__ fG2, u16* __restrict__ fPQ,
    u16* __restrict__ fDec, u16* __restrict__ fEnc,
    const int* __restrict__ srcp, const int* __restrict__ tgtp, const float* __restrict__ eattr,
    int* __restrict__ cnt, float4* __restrict__ sea) {
    if (blockIdx.x >= 442) {
        int e = (blockIdx.x - 442) * 256 + threadIdx.x;
        if (e < NE) {
            int t = tgtp[e];
            int pos = atomicAdd(&cnt[t], 1);
            if (pos < CAP) {
                sea[t * CAP + pos] = make_float4(eattr[e * 3], eattr[e * 3 + 1], eattr[e * 3 + 2],
                                                 __uint_as_float((unsigned)srcp[e]));
            }
        }
        return;
    }
    int idx = blockIdx.x * 256 + threadIdx.x;
    if (idx < 65536) {
        int l = idx >> 14, rem = idx & 16383, i = rem >> 7, jj = rem & 127;
        const float* U1b = upd_w1 + (size_t)l * 2 * HD * HD + (size_t)HD * HD;
        const float* W2 = msg_w2 + (size_t)l * HD * HD + (size_t)i * HD;
        float acc = 0.f;
        for (int t = 0; t < HD; ++t) acc += W2[t] * U1b[(size_t)t * HD + jj];
        int ct = jj >> 4;
        int ks = 4 + (i >> 5);
        int lane = (((i & 31) >> 3) << 4) | (jj & 15);
        int j = i & 7;
        int g = (l << 12) | (ct << 9) | (ks << 6) | lane;
        fG1[(size_t)g * 8 + j] = f2bf(acc);
    } else if (idx < 66048) {
        int r = idx - 65536;
        int l = r >> 7, jj = r & 127;
        const float* U1b = upd_w1 + (size_t)l * 2 * HD * HD + (size_t)HD * HD;
        const float* b2 = msg_b2 + l * HD;
        float acc = 0.f;
        for (int t = 0; t < HD; ++t) acc += b2[t] * U1b[(size_t)t * HD + jj];
        c2[r] = acc;
    } else if (idx < 76048) {
        // dead
    } else if (idx < 84240) {
        int gl = idx - 76048;
        int l = gl >> 11, rem = gl & 2047;
        int ct = rem >> 8, ks = (rem >> 6) & 3, lane = rem & 63;
        int n = ct * 16 + (lane & 15), kb = ks * 32 + ((lane >> 4) << 3);
        int g = (l << 12) | (ct << 9) | (ks << 6) | lane;
        u16* dst = fG1 + (size_t)g * 8;
        const float* U = upd_w1 + (size_t)l * 256 * 128;
#pragma unroll
        for (int j = 0; j < 8; ++j) dst[j] = f2bf(U[(size_t)(kb + j) * 128 + n]);
    } else if (idx < 92432) {
        int gg = idx - 84240;
        int l = gg >> 11, r = gg & 2047;
        int ct = r >> 8, ks = (r >> 6) & 3, lane = r & 63;
        int n = ct * 16 + (lane & 15), kb = ks * 32 + ((lane >> 4) << 3);
        u16* dst = fG2 + (size_t)gg * 8;
        const float* W = upd_w2 + (size_t)l * 128 * 128;
#pragma unroll
        for (int j = 0; j < 8; ++j) dst[j] = f2bf(W[(size_t)(kb + j) * 128 + n]);
    } else if (idx < 108816) {
        int gg = idx - 92432;
        int li = gg >> 12, r = gg & 4095;
        int ct = r >> 8, ks = (r >> 6) & 3, lane = r & 63;
        int n = ct * 16 + (lane & 15), kb = ks * 32 + ((lane >> 4) << 3);
        u16* dst = fPQ + (size_t)gg * 8;
        const float* W = msg_w1 + (size_t)li * (2 * HD + EDIM) * HD;
#pragma unroll
        for (int j = 0; j < 8; ++j) {
            int k = kb + j;
            float v = (n < 128) ? W[(size_t)k * 128 + n] : W[(size_t)(128 + k) * 128 + (n - 128)];
            dst[j] = f2bf(v);
        }
    } else if (idx < 110864) {
        int r = idx - 108816;
        int ct = r >> 8, ks = (r >> 6) & 3, lane = r & 63;
        int n = ct * 16 + (lane & 15), kb = ks * 32 + ((lane >> 4) << 3);
        u16* dst = fDec + (size_t)r * 8;
#pragma unroll
        for (int j = 0; j < 8; ++j) dst[j] = f2bf(dec_w1[(size_t)(kb + j) * 128 + n]);
    } else if (idx < 112912) {
        int r = idx - 110864;
        int ct = r >> 8, ks = (r >> 6) & 3, lane = r & 63;
        int n = ct * 16 + (lane & 15), kb = ks * 32 + ((lane >> 4) << 3);
        u16* dst = fEnc + (size_t)r * 8;
#pragma unroll
        for (int j = 0; j < 8; ++j) dst[j] = f2bf(enc_w2[(size_t)(kb + j) * 128 + n]);
    }
}

// ---- k_enc: encoder (16 nodes per block) + PQ0 precompute ----

__global__ __launch_bounds__(512) void k_enc(
    const float* __restrict__ x, const float* __restrict__ ew1, const float* __restrict__ eb1,
    const u16* __restrict__ fEnc, const float* __restrict__ eb2, const u16* __restrict__ fPQ0,
    const float* __restrict__ mb1, u16* __restrict__ h_hi, u16* __restrict__ h_lo,
    float* __restrict__ PQf, u16* __restrict__ Qb) {
    __shared__ u16 tHi[2048], tLo[2048];
    int tid = threadIdx.x, w = tid >> 6, lane = tid & 63, q = lane >> 4, c = lane & 15;
    int band = blockIdx.x * 16;
    {
        int col = w * 16 + c;
        float wv[NIN];
#pragma unroll
        for (int k = 0; k < NIN; ++k) wv[k] = ew1[k * HD + col];
        float ebv = eb1[col];
#pragma unroll
        for (int reg = 0; reg < 4; ++reg) {
            int row = band + q * 4 + reg;
            float t = ebv;
#pragma unroll
            for (int k = 0; k < NIN; ++k) t += x[(size_t)row * NIN + k] * wv[k];
            t = fmaxf(t, 0.f);
            u16 hi, lo;
            split2(t, hi, lo);
            int r16 = q * 4 + reg;
            int a = r16 * 128 + (((col >> 3) ^ r16) << 3) + (col & 7);
            tHi[a] = hi;
            tLo[a] = lo;
        }
    }
    __syncthreads();
    short8 aH[4], aL[4];
#pragma unroll
    for (int ks = 0; ks < 4; ++ks) {
        int a = c * 128 + (((ks * 4 + q) ^ c) << 3);
        aH[ks] = *(const short8*)&tHi[a];
        aL[ks] = *(const short8*)&tLo[a];
    }
    f32x4 acc = {0, 0, 0, 0};
    {
        const u16* fb = fEnc + (size_t)w * 4 * 512 + lane * 8;
#pragma unroll
        for (int ks = 0; ks < 4; ++ks) {
            short8 b = *(const short8*)(fb + ks * 512);
            acc = MFMA(aH[ks], b, acc);
            acc = MFMA(aL[ks], b, acc);
        }
    }
    __syncthreads();
    {
        int col = w * 16 + c;
        float ebv = eb2[col];
#pragma unroll
        for (int reg = 0; reg < 4; ++reg) {
            int r16 = q * 4 + reg, row = band + r16;
            float hval = acc[reg] + ebv;
            u16 hi, lo;
            split2(hval, hi, lo);
            h_hi[(size_t)row * HD + col] = hi;
            h_lo[(size_t)row * HD + col] = lo;
            int a = r16 * 128 + (((col >> 3) ^ r16) << 3) + (col & 7);
            tHi[a] = hi;
            tLo[a] = lo;
        }
    }
    __syncthreads();
#pragma unroll
    for (int ks = 0; ks < 4; ++ks) {
        int a = c * 128 + (((ks * 4 + q) ^ c) << 3);
        aH[ks] = *(const short8*)&tHi[a];
        aL[ks] = *(const short8*)&tLo[a];
    }
#pragma unroll
    for (int i = 0; i < 2; ++i) {
        int ctg = w * 2 + i;
        const u16* fb = fPQ0 + (size_t)ctg * 4 * 512 + lane * 8;
        f32x4 a3 = {0, 0, 0, 0};
#pragma unroll
        for (int ks = 0; ks < 4; ++ks) {
            short8 b = *(const short8*)(fb + ks * 512);
            a3 = MFMA(aH[ks], b, a3);
            a3 = MFMA(aL[ks], b, a3);
        }
        int col = ctg * 16 + c;
        if (ctg < 8) {
            float bias = mb1[col];
#pragma unroll
            for (int reg = 0; reg < 4; ++reg)
                PQf[(size_t)(band + q * 4 + reg) * HD + col] = a3[reg] + bias;
        } else {
            int colq = col - 128;
#pragma unroll
            for (int reg = 0; reg < 4; ++reg)
                Qb[(size_t)(band + q * 4 + reg) * HD + colq] = f2bf(a3[reg]);
        }
    }
}

// ------- fused layer (512 thr / 8 waves): gather -> G1 -> G2 -> LN -> (PQ | dec) -----
// Edge gather: wave w handles nodes band+w*2, band+w*2+1 sequentially with the
// R6-proven batch-8 two-stage pipeline (scalar bucket loads + Qb row gathers in
// flight across batch boundaries, dual even/odd accumulators, clamped tail).
// Aggregate stays in LDS (sHi/sLo) — no global agg buffers, no extra launches.
// Gather order per node identical to the split k_gath (bit-identical output).

template <bool LAST>
__global__ __launch_bounds__(512) void k_layer(
    const float* __restrict__ PQf_in, const u16* __restrict__ Qb_in,
    const int* __restrict__ cnt, const float4* __restrict__ sea, const float* __restrict__ wc,
    u16* __restrict__ h_hi, u16* __restrict__ h_lo,
    const u16* __restrict__ fG1, const u16* __restrict__ fG2,
    const float* __restrict__ ub1, const float* __restrict__ c2l, const float* __restrict__ ub2,
    const float* __restrict__ g, const float* __restrict__ bb,
    const u16* __restrict__ fPQ, const float* __restrict__ nb1,
    float* __restrict__ PQf_out, u16* __restrict__ Qb_out,
    const u16* __restrict__ fDec, const float* __restrict__ db1, const float* __restrict__ dw2,
    const float* __restrict__ db2, float* __restrict__ out) {
    __shared__ u16 sHi[2048], sLo[2048];
    __shared__ u16 tHi[2048], tLo[2048];
    __shared__ float red[16][8][2];
    int tid = threadIdx.x, w = tid >> 6, lane = tid & 63, q = lane >> 4, c = lane & 15;
    int band = blockIdx.x * 16;
    int j = lane * 2;
    // ======== edge gather phase ========
    {
        float2 wcr0 = *(const float2*)(wc + j);
        float2 wcr1 = *(const float2*)(wc + HD + j);
        float2 wcr2 = *(const float2*)(wc + 2 * HD + j);
#pragma unroll
        for (int i = 0; i < 2; ++i) {
            int r16 = w * 2 + i;
            int n = __builtin_amdgcn_readfirstlane(band + r16);
            int cn = cnt[n];
            int cle = __builtin_amdgcn_readfirstlane(cn < CAP ? cn : CAP);
            float2 p = *(const float2*)(PQf_in + (size_t)n * HD + j);
            const float4* bk = sea + (size_t)n * CAP;
            float e0 = 0.f, e1 = 0.f, o0 = 0.f, o1 = 0.f;
            float4 A0[8], A1[8];
            unsigned U0[8], U1[8];

            auto LA = [&](float4* A, int b) {
#pragma unroll
                for (int k = 0; k < 8; ++k) A[k] = bk[b * 8 + k];
            };
            auto IU = [&](unsigned* U, const float4* A) {
#pragma unroll
                for (int k = 0; k < 8; ++k)
                    U[k] = *(const unsigned*)(Qb_in + (size_t)__float_as_uint(A[k].w) * HD + j);
            };
            auto CO = [&](const float4* A, const unsigned* U) {
#pragma unroll
                for (int k = 0; k < 8; ++k) {
                    float c0 = A[k].x * wcr0.x + A[k].y * wcr1.x + A[k].z * wcr2.x;
                    float c1 = A[k].x * wcr0.y + A[k].y * wcr1.y + A[k].z * wcr2.y;
                    float t0 = fmaxf(p.x + __uint_as_float(U[k] << 16) + c0, 0.f);
                    float t1 = fmaxf(p.y + __uint_as_float(U[k] & 0xffff0000u) + c1, 0.f);
                    if (k & 1) { o0 += t0; o1 += t1; } else { e0 += t0; e1 += t1; }
                }
            };

            int nb = cle >> 3;
            int b = 0;
            if (nb) {
                LA(A0, 0);
                IU(U0, A0);
                for (; b + 2 <= nb; b += 2) {
                    LA(A1, b + 1);
                    IU(U1, A1);
                    CO(A0, U0);
                    if (b + 2 < nb) { LA(A0, b + 2); IU(U0, A0); }
                    CO(A1, U1);
                }
                if (b < nb) { CO(A0, U0); ++b; }
            }
            int e = nb * 8;
            int rem = cle - e;
            if (rem) {
#pragma unroll
                for (int k = 0; k < 8; ++k) A0[k] = bk[e + (k < rem ? k : 0)];
                IU(U0, A0);
#pragma unroll
                for (int k = 0; k < 8; ++k) {
                    float c0 = A0[k].x * wcr0.x + A0[k].y * wcr1.x + A0[k].z * wcr2.x;
                    float c1 = A0[k].x * wcr0.y + A0[k].y * wcr1.y + A0[k].z * wcr2.y;
                    float t0 = fmaxf(p.x + __uint_as_float(U0[k] << 16) + c0, 0.f);
                    float t1 = fmaxf(p.y + __uint_as_float(U0[k] & 0xffff0000u) + c1, 0.f);
                    t0 = (k < rem) ? t0 : 0.f;
                    t1 = (k < rem) ? t1 : 0.f;
                    if (k & 1) { o0 += t0; o1 += t1; } else { e0 += t0; e1 += t1; }
                }
            }
            float invn = 1.0f / fmaxf((float)cn, 1.0f);
            float v0 = (e0 + o0) * invn, v1 = (e1 + o1) * invn;
            u16 h0, l0, h1, l1;
            split2(v0, h0, l0);
            split2(v1, h1, l1);
            int a = r16 * 128 + (((j >> 3) ^ r16) << 3) + (j & 7);
            *(ushort2*)&sHi[a] = make_ushort2(h0, h1);
            *(ushort2*)&sLo[a] = make_ushort2(l0, l1);
        }
    }
    __syncthreads();
    // ======== G1: A = [h (global) | S (LDS)], dual accumulators ========
    short8 aH[8], aL[8];
    {
        size_t rb = (size_t)(band + c) * HD + q * 8;
#pragma unroll
        for (int ks = 0; ks < 4; ++ks) {
            aH[ks] = *(const short8*)(h_hi + rb + ks * 32);
            aL[ks] = *(const short8*)(h_lo + rb + ks * 32);
            int a = c * 128 + (((ks * 4 + q) ^ c) << 3);
            aH[4 + ks] = *(const short8*)&sHi[a];
            aL[4 + ks] = *(const short8*)&sLo[a];
        }
    }
    f32x4 accA = {0, 0, 0, 0}, accB = {0, 0, 0, 0};
    {
        const u16* fb = fG1 + (size_t)w * 8 * 512 + lane * 8;
#pragma unroll
        for (int ks = 0; ks < 4; ++ks) {
            short8 bA = *(const short8*)(fb + ks * 512);
            short8 bB = *(const short8*)(fb + (ks + 4) * 512);
            accA = MFMA(aH[ks], bA, accA);
            accB = MFMA(aH[ks + 4], bB, accB);
            accA = MFMA(aL[ks], bA, accA);
            accB = MFMA(aL[ks + 4], bB, accB);
        }
    }
    f32x4 acc = accA + accB;
    float alv[4];
#pragma unroll
    for (int reg = 0; reg < 4; ++reg) alv[reg] = (cnt[band + q * 4 + reg] > 0) ? 1.f : 0.f;
    {
        int col = w * 16 + c;
        float u1b = ub1[col], cc = c2l[col];
#pragma unroll
        for (int reg = 0; reg < 4; ++reg) {
            int r16 = q * 4 + reg;
            float t = fmaxf(acc[reg] + u1b + alv[reg] * cc, 0.f);
            u16 hi, lo;
            split2(t, hi, lo);
            int a = r16 * 128 + (((col >> 3) ^ r16) << 3) + (col & 7);
            tHi[a] = hi;
            tLo[a] = lo;
        }
    }
    __syncthreads();
    // ======== G2: dual accumulators ========
    short8 aH2[4], aL2[4];
#pragma unroll
    for (int ks = 0; ks < 4; ++ks) {
        int a = c * 128 + (((ks * 4 + q) ^ c) << 3);
        aH2[ks] = *(const short8*)&tHi[a];
        aL2[ks] = *(const short8*)&tLo[a];
    }
    f32x4 acc2A = {0, 0, 0, 0}, acc2B = {0, 0, 0, 0};
    {
        const u16* fb = fG2 + (size_t)w * 4 * 512 + lane * 8;
#pragma unroll
        for (int ks = 0; ks < 2; ++ks) {
            short8 bA = *(const short8*)(fb + ks * 512);
            short8 bB = *(const short8*)(fb + (ks + 2) * 512);
            acc2A = MFMA(aH2[ks], bA, acc2A);
            acc2B = MFMA(aH2[ks + 2], bB, acc2B);
            acc2A = MFMA(aL2[ks], bA, acc2A);
            acc2B = MFMA(aL2[ks + 2], bB, acc2B);
        }
    }
    f32x4 acc2 = acc2A + acc2B;
    // ======== residual + LN ========
    float vv[4];
    {
        int col = w * 16 + c;
        float u2b = ub2[col];
#pragma unroll
        for (int reg = 0; reg < 4; ++reg) {
            size_t idx = (size_t)(band + q * 4 + reg) * HD + col;
            float hres = bf2f(h_hi[idx]) + bf2f(h_lo[idx]);
            vv[reg] = acc2[reg] + u2b + hres;
        }
    }
#pragma unroll
    for (int reg = 0; reg < 4; ++reg) {
        float s = vv[reg];
        float s2 = vv[reg] * vv[reg];
        for (int m = 1; m < 16; m <<= 1) {
            s += __shfl_xor(s, m);
            s2 += __shfl_xor(s2, m);
        }
        if (c == 0) {
            red[q * 4 + reg][w][0] = s;
            red[q * 4 + reg][w][1] = s2;
        }
    }
    __syncthreads();
    float mu[4], rs[4];
#pragma unroll
    for (int reg = 0; reg < 4; ++reg) {
        int r16 = q * 4 + reg;
        float S1 = 0.f, S2 = 0.f;
#pragma unroll
        for (int ww = 0; ww < 8; ++ww) {
            S1 += red[r16][ww][0];
            S2 += red[r16][ww][1];
        }
        float m = S1 * (1.f / HD);
        float var = S2 * (1.f / HD) - m * m;
        mu[reg] = m;
        rs[reg] = rsqrtf(var + LN_EPS);
    }
    {
        int col = w * 16 + c;
        float gg = g[col], bv = bb[col];
#pragma unroll
        for (int reg = 0; reg < 4; ++reg) {
            int r16 = q * 4 + reg;
            float o = (vv[reg] - mu[reg]) * rs[reg] * gg + bv;
            u16 hi, lo;
            split2(o, hi, lo);
            int a = r16 * 128 + (((col >> 3) ^ r16) << 3) + (col & 7);
            tHi[a] = hi;
            tLo[a] = lo;
            if (!LAST) {
                size_t idx = (size_t)(band + r16) * HD + col;
                h_hi[idx] = hi;
                h_lo[idx] = lo;
            }
        }
    }
    __syncthreads();
    short8 aH3[4], aL3[4];
#pragma unroll
    for (int ks = 0; ks < 4; ++ks) {
        int a = c * 128 + (((ks * 4 + q) ^ c) << 3);
        aH3[ks] = *(const short8*)&tHi[a];
        aL3[ks] = *(const short8*)&tLo[a];
    }
    if (!LAST) {
#pragma unroll
        for (int i = 0; i < 2; ++i) {
            int ctg = w * 2 + i;
            const u16* fb = fPQ + (size_t)ctg * 4 * 512 + lane * 8;
            f32x4 a3A = {0, 0, 0, 0}, a3B = {0, 0, 0, 0};
#pragma unroll
            for (int ks = 0; ks < 2; ++ks) {
                short8 bA = *(const short8*)(fb + ks * 512);
                short8 bB = *(const short8*)(fb + (ks + 2) * 512);
                a3A = MFMA(aH3[ks], bA, a3A);
                a3B = MFMA(aH3[ks + 2], bB, a3B);
                a3A = MFMA(aL3[ks], bA, a3A);
                a3B = MFMA(aL3[ks + 2], bB, a3B);
            }
            f32x4 a3 = a3A + a3B;
            int col = ctg * 16 + c;
            if (ctg < 8) {
                float bias = nb1[col];
#pragma unroll
                for (int reg = 0; reg < 4; ++reg)
                    PQf_out[(size_t)(band + q * 4 + reg) * HD + col] = a3[reg] + bias;
            } else {
                int colq = col - 128;
#pragma unroll
                for (int reg = 0; reg < 4; ++reg)
                    Qb_out[(size_t)(band + q * 4 + reg) * HD + colq] = f2bf(a3[reg]);
            }
        }
    } else {
        float part[4];
        {
            const u16* fb = fDec + (size_t)w * 4 * 512 + lane * 8;
            f32x4 a3A = {0, 0, 0, 0}, a3B = {0, 0, 0, 0};
#pragma unroll
            for (int ks = 0; ks < 2; ++ks) {
                short8 bA = *(const short8*)(fb + ks * 512);
                short8 bB = *(const short8*)(fb + (ks + 2) * 512);
                a3A = MFMA(aH3[ks], bA, a3A);
                a3B = MFMA(aH3[ks + 2], bB, a3B);
                a3A = MFMA(aL3[ks], bA, a3A);
                a3B = MFMA(aL3[ks + 2], bB, a3B);
            }
            f32x4 a3 = a3A + a3B;
            int col = w * 16 + c;
            float w2v = dw2[col], b1v = db1[col];
#pragma unroll
            for (int reg = 0; reg < 4; ++reg) part[reg] = fmaxf(a3[reg] + b1v, 0.f) * w2v;
        }
#pragma unroll
        for (int reg = 0; reg < 4; ++reg) {
            float s = part[reg];
            for (int m = 1; m < 16; m <<= 1) s += __shfl_xor(s, m);
            if (c == 0) red[q * 4 + reg][w][0] = s;
        }
        __syncthreads();
        if (tid < 16) {
            float s = db2[0];
#pragma unroll
            for (int ww = 0; ww < 8; ++ww) s += red[tid][ww][0];
            out[band + tid] = s;
        }
    }
}

// ---------------- launch ----------------

extern "C" void kernel_launch(void* const* d_in, const int* in_sizes, int n_in,
                              void* d_out, int out_size, void* d_ws, size_t ws_size,
                              hipStream_t stream) {
    const float* x = (const float*)d_in[0];
    const int* eidx = (const int*)d_in[1];
    const float* eattr = (const float*)d_in[2];
    const float* enc_w1 = (const float*)d_in[3];
    const float* enc_b1 = (const float*)d_in[4];
    const float* enc_w2 = (const float*)d_in[5];
    const float* enc_b2 = (const float*)d_in[6];
    const float* msg_w1 = (const float*)d_in[7];
    const float* msg_b1 = (const float*)d_in[8];
    const float* msg_w2 = (const float*)d_in[9];
    const float* msg_b2 = (const float*)d_in[10];
    const float* upd_w1 = (const float*)d_in[11];
    const float* upd_b1 = (const float*)d_in[12];
    const float* upd_w2 = (const float*)d_in[13];
    const float* upd_b2 = (const float*)d_in[14];
    const float* ln_g = (const float*)d_in[15];
    const float* ln_b = (const float*)d_in[16];
    const float* dec_w1 = (const float*)d_in[17];
    const float* dec_b1 = (const float*)d_in[18];
    const float* dec_w2 = (const float*)d_in[19];
    const float* dec_b2 = (const float*)d_in[20];
    const int* srcp = eidx;
    const int* tgtp = eidx + NE;

    char* base = (char*)d_ws;
    size_t off = 0;
    auto alloc = [&](size_t bytes) -> void* {
        off = (off + 15) & ~(size_t)15;
        void* p = base + off;
        off += bytes;
        return p;
    };
    float4* sea = (float4*)alloc((size_t)NN * CAP * 16);
    float* PQf0 = (float*)alloc((size_t)NN * HD * 4);
    float* PQf1 = (float*)alloc((size_t)NN * HD * 4);
    u16* Qb0 = (u16*)alloc((size_t)NN * HD * 2);
    u16* Qb1 = (u16*)alloc((size_t)NN * HD * 2);
    u16* h_hi = (u16*)alloc((size_t)NN * HD * 2);
    u16* h_lo = (u16*)alloc((size_t)NN * HD * 2);
    int* cnt = (int*)alloc((size_t)NN * 4);
    float* c2 = (float*)alloc((size_t)NL * HD * 4);
    u16* fG1 = (u16*)alloc((size_t)131072 * 2);
    u16* fG2 = (u16*)alloc((size_t)65536 * 2);
    u16* fPQ = (u16*)alloc((size_t)131072 * 2);
    u16* fDec = (u16*)alloc((size_t)16384 * 2);
    u16* fEnc = (u16*)alloc((size_t)16384 * 2);

    hipMemsetAsync(cnt, 0, (size_t)NN * 4, stream);
    k_prepscat<<<442 + (NE + 255) / 256, 256, 0, stream>>>(
        msg_w2, msg_b2, upd_w1, upd_w2, msg_w1, dec_w1, enc_w2,
        c2, fG1, fG2, fPQ, fDec, fEnc,
        srcp, tgtp, eattr, cnt, sea);
    k_enc<<<625, 512, 0, stream>>>(x, enc_w1, enc_b1, fEnc, enc_b2, fPQ,
                                   msg_b1, h_hi, h_lo, PQf0, Qb0);

    float* PQin = PQf0;
    u16* Qin = Qb0;
    float* PQout = PQf1;
    u16* Qout = Qb1;
    for (int l = 0; l < NL; ++l) {
        const float* wc = msg_w1 + (size_t)l * (2 * HD + EDIM) * HD + (size_t)2 * HD * HD;
        if (l < NL - 1) {
            k_layer<false><<<NN / 16, 512, 0, stream>>>(
                PQin, Qin, cnt, sea, wc, h_hi, h_lo,
                fG1 + (size_t)l * 32768, fG2 + (size_t)l * 16384,
                upd_b1 + l * HD, c2 + l * HD, upd_b2 + l * HD, ln_g + l * HD, ln_b + l * HD,
                fPQ + (size_t)(l + 1) * 32768, msg_b1 + (size_t)(l + 1) * HD, PQout, Qout,
                nullptr, nullptr, nullptr, nullptr, nullptr);
        } else {
            k_layer<true><<<NN / 16, 512, 0, stream>>>(
                PQin, Qin, cnt, sea, wc, h_hi, h_lo,
                fG1 + (size_t)l * 32768, fG2 + (size_t)l * 16384,
                upd_b1 + l * HD, c2 + l * HD, upd_b2 + l * HD, ln_g + l * HD, ln_b + l * HD,
                nullptr, nullptr, nullptr, nullptr,
                fDec, dec_b1, dec_w2, dec_b2, (float*)d_out);
        }
        float* tf = PQin; PQin = PQout; PQout = tf;
        u16* tq = Qin; Qin = Qout; Qout = tq;
    }
}